// Round 1
// baseline (1336.596 us; speedup 1.0000x reference)
//
#include <hip/hip_runtime.h>
#include <cstdint>
#include <cstddef>

typedef unsigned short ushort_t;
typedef short s16x8 __attribute__((ext_vector_type(8)));
typedef float f32x4 __attribute__((ext_vector_type(4)));

// ---------- small helpers ----------
__device__ __forceinline__ float bf2f(ushort_t h){
  union { unsigned int u; float f; } v; v.u = ((unsigned int)h) << 16; return v.f;
}
__device__ __forceinline__ ushort_t f2bf(float x){
  union { float f; unsigned int u; } v; v.f = x;
  unsigned int r = v.u + 0x7FFFu + ((v.u >> 16) & 1u);
  return (ushort_t)(r >> 16);
}
__device__ __forceinline__ float gelu_f(float x){
  return 0.5f * x * (1.0f + erff(x * 0.7071067811865475f));
}
__device__ __forceinline__ float wave_sum(float v){
  #pragma unroll
  for (int o = 32; o; o >>= 1) v += __shfl_xor(v, o);
  return v;
}
__device__ __forceinline__ float wave_max(float v){
  #pragma unroll
  for (int o = 32; o; o >>= 1) v = fmaxf(v, __shfl_xor(v, o));
  return v;
}
__device__ __forceinline__ void block_reduce2(float& s, float& q, float* red){
  s = wave_sum(s); q = wave_sum(q);
  int w = threadIdx.x >> 6, lane = threadIdx.x & 63, nw = blockDim.x >> 6;
  if (lane == 0){ red[w] = s; red[8 + w] = q; }
  __syncthreads();
  float ts = 0.f, tq = 0.f;
  for (int i = 0; i < nw; ++i){ ts += red[i]; tq += red[8 + i]; }
  __syncthreads();
  s = ts; q = tq;
}

// ---------- weight prep ----------
// out[n][k] = (bf16) in[k][n]; K,N multiples of 32
__global__ void transpose_cast_k(const float* __restrict__ in, ushort_t* __restrict__ out, int K, int N){
  __shared__ float t[32][33];
  int n0 = blockIdx.x * 32, k0 = blockIdx.y * 32;
  int tx = threadIdx.x, ty = threadIdx.y;
  #pragma unroll
  for (int j = 0; j < 32; j += 8){
    t[ty + j][tx] = in[(size_t)(k0 + ty + j) * N + (n0 + tx)];
  }
  __syncthreads();
  #pragma unroll
  for (int j = 0; j < 32; j += 8){
    out[(size_t)(n0 + ty + j) * K + (k0 + tx)] = f2bf(t[tx][ty + j]);
  }
}

__global__ void cast4_k(const float* __restrict__ in, ushort_t* __restrict__ out, int n){
  int i = (blockIdx.x * 256 + threadIdx.x) * 4;
  if (i >= n) return;
  float4 v = *(const float4*)(in + i);
  union { ushort_t u[4]; uint2 p; } pk;
  pk.u[0] = f2bf(v.x); pk.u[1] = f2bf(v.y); pk.u[2] = f2bf(v.z); pk.u[3] = f2bf(v.w);
  *(uint2*)(out + i) = pk.p;
}

// ---------- LN kernels ----------
// trunk: concat(states[512], time_embed[128]) -> LN(640) -> bf16
__global__ __launch_bounds__(256) void ln_trunk_k(const float* __restrict__ states, const float* __restrict__ tv,
    const float* __restrict__ g, const float* __restrict__ b, ushort_t* __restrict__ out){
  int row = blockIdx.x, tid = threadIdx.x;
  __shared__ float buf[640];
  __shared__ float red[16];
  float t = tv[row];
  for (int i = tid; i < 640; i += 256){
    float v;
    if (i < 512) v = states[(size_t)row * 512 + i];
    else {
      int j = i - 512, jj = j & 63;
      float fr = expf(6.907755278982137f * ((float)jj * (1.0f / 63.0f)));
      float ang = 6.283185307179586f * t * fr;
      v = (j < 64) ? sinf(ang) : cosf(ang);
    }
    buf[i] = v;
  }
  __syncthreads();
  float s = 0.f, q = 0.f;
  for (int i = tid; i < 640; i += 256){ float v = buf[i]; s += v; q += v * v; }
  block_reduce2(s, q, red);
  float mean = s * (1.0f / 640.0f);
  float var = q * (1.0f / 640.0f) - mean * mean;
  float rstd = rsqrtf(var + 1e-5f);
  for (int i = tid; i < 640; i += 256)
    out[(size_t)row * 640 + i] = f2bf((buf[i] - mean) * rstd * g[i] + b[i]);
}

// mem LN: one wave per 512-elem row, 4 rows per block
__global__ __launch_bounds__(256) void ln_mem_k(const float* __restrict__ sm, const float* __restrict__ g,
    const float* __restrict__ b, ushort_t* __restrict__ out){
  int tid = threadIdx.x, w = tid >> 6, lane = tid & 63;
  size_t row = (size_t)blockIdx.x * 4 + w;
  const float* r = sm + row * 512 + lane * 8;
  float4 a = *(const float4*)r;
  float4 c = *(const float4*)(r + 4);
  float vals[8] = { a.x, a.y, a.z, a.w, c.x, c.y, c.z, c.w };
  float s = 0.f, q = 0.f;
  #pragma unroll
  for (int e = 0; e < 8; ++e){ s += vals[e]; q += vals[e] * vals[e]; }
  s = wave_sum(s); q = wave_sum(q);
  float mean = s * (1.0f / 512.0f);
  float var = q * (1.0f / 512.0f) - mean * mean;
  float rstd = rsqrtf(var + 1e-5f);
  const float* gp = g + lane * 8;
  const float* bp = b + lane * 8;
  union { ushort_t u[8]; uint4 p; } pk;
  #pragma unroll
  for (int e = 0; e < 8; ++e) pk.u[e] = f2bf((vals[e] - mean) * rstd * gp[e] + bp[e]);
  *(uint4*)(out + row * 512 + lane * 8) = pk.p;
}

// generic row LN (D=1024, 4 elems/thread), f32 in -> bf16 out
__global__ __launch_bounds__(256) void ln_rows_k(const float* __restrict__ in, const float* __restrict__ g,
    const float* __restrict__ b, ushort_t* __restrict__ out, int D){
  int row = blockIdx.x, tid = threadIdx.x, i = tid * 4;
  __shared__ float red[16];
  const float* x = in + (size_t)row * D;
  float4 v = *(const float4*)(x + i);
  float s = v.x + v.y + v.z + v.w;
  float q = v.x * v.x + v.y * v.y + v.z * v.z + v.w * v.w;
  block_reduce2(s, q, red);
  float invD = 1.0f / (float)D;
  float mean = s * invD, var = q * invD - mean * mean, rstd = rsqrtf(var + 1e-5f);
  union { ushort_t u[4]; uint2 p; } pk;
  pk.u[0] = f2bf((v.x - mean) * rstd * g[i + 0] + b[i + 0]);
  pk.u[1] = f2bf((v.y - mean) * rstd * g[i + 1] + b[i + 1]);
  pk.u[2] = f2bf((v.z - mean) * rstd * g[i + 2] + b[i + 2]);
  pk.u[3] = f2bf((v.w - mean) * rstd * g[i + 3] + b[i + 3]);
  *(uint2*)(out + (size_t)row * D + i) = pk.p;
}

// combined = LN(g+as); c2 = (1+scale)*combined + shift; cx = LN(c2)
__global__ __launch_bounds__(256) void fuse_film_k(const float* __restrict__ gf, const float* __restrict__ asf,
    const float* __restrict__ film, const float* __restrict__ pg, const float* __restrict__ pb,
    const float* __restrict__ cg, const float* __restrict__ cb,
    float* __restrict__ c2f, ushort_t* __restrict__ cxb){
  int row = blockIdx.x, tid = threadIdx.x, i = tid * 4;
  __shared__ float red[16];
  float4 a = *(const float4*)(gf + (size_t)row * 1024 + i);
  float4 d = *(const float4*)(asf + (size_t)row * 1024 + i);
  float x[4] = { a.x + d.x, a.y + d.y, a.z + d.z, a.w + d.w };
  float s = x[0] + x[1] + x[2] + x[3];
  float q = x[0]*x[0] + x[1]*x[1] + x[2]*x[2] + x[3]*x[3];
  block_reduce2(s, q, red);
  float mean = s * (1.0f / 1024.0f), var = q * (1.0f / 1024.0f) - mean * mean;
  float rstd = rsqrtf(var + 1e-5f);
  float4 pgv = *(const float4*)(pg + i), pbv = *(const float4*)(pb + i);
  float4 sc = *(const float4*)(film + (size_t)row * 2048 + i);
  float4 sh = *(const float4*)(film + (size_t)row * 2048 + 1024 + i);
  float c2[4];
  {
    float pgx[4] = { pgv.x, pgv.y, pgv.z, pgv.w };
    float pbx[4] = { pbv.x, pbv.y, pbv.z, pbv.w };
    float scx[4] = { sc.x, sc.y, sc.z, sc.w };
    float shx[4] = { sh.x, sh.y, sh.z, sh.w };
    #pragma unroll
    for (int e = 0; e < 4; ++e){
      float cc = (x[e] - mean) * rstd * pgx[e] + pbx[e];
      c2[e] = (1.0f + scx[e]) * cc + shx[e];
    }
  }
  *(float4*)(c2f + (size_t)row * 1024 + i) = make_float4(c2[0], c2[1], c2[2], c2[3]);
  float s2 = c2[0] + c2[1] + c2[2] + c2[3];
  float q2 = c2[0]*c2[0] + c2[1]*c2[1] + c2[2]*c2[2] + c2[3]*c2[3];
  block_reduce2(s2, q2, red);
  float m2 = s2 * (1.0f / 1024.0f), v2 = q2 * (1.0f / 1024.0f) - m2 * m2;
  float r2 = rsqrtf(v2 + 1e-5f);
  float4 cgv = *(const float4*)(cg + i), cbv = *(const float4*)(cb + i);
  union { ushort_t u[4]; uint2 p; } pk;
  pk.u[0] = f2bf((c2[0] - m2) * r2 * cgv.x + cbv.x);
  pk.u[1] = f2bf((c2[1] - m2) * r2 * cgv.y + cbv.y);
  pk.u[2] = f2bf((c2[2] - m2) * r2 * cgv.z + cbv.z);
  pk.u[3] = f2bf((c2[3] - m2) * r2 * cgv.w + cbv.w);
  *(uint2*)(cxb + (size_t)row * 1024 + i) = pk.p;
}

// ---------- attention (per-b): logits = SCALE * memh[b] @ qk[b]^T, softmax over m, ctx = attn @ memh[b] ----------
__global__ __launch_bounds__(256) void attn_k(const ushort_t* __restrict__ qk, const ushort_t* __restrict__ memh,
                                              ushort_t* __restrict__ ctx){
  int b = blockIdx.x;
  __shared__ ushort_t qks[8192];      // 8 heads x 1024
  __shared__ float lg[8][64];
  __shared__ float at[8][64];
  int tid = threadIdx.x, w = tid >> 6, lane = tid & 63;
  {
    const uint4* s = (const uint4*)(qk + (size_t)b * 8192);
    uint4* d = (uint4*)qks;
    for (int i = tid; i < 1024; i += 256) d[i] = s[i];
  }
  __syncthreads();
  const ushort_t* mb = memh + (size_t)b * 65536;
  // cache q fragments in registers (per-lane j-slices: [lane*8, lane*8+8) and [512+lane*8, ...))
  s16x8 qr0[8], qr1[8];
  #pragma unroll
  for (int h = 0; h < 8; ++h){
    qr0[h] = *(const s16x8*)(qks + h * 1024 + lane * 8);
    qr1[h] = *(const s16x8*)(qks + h * 1024 + 512 + lane * 8);
  }
  for (int mi = 0; mi < 16; ++mi){
    int m = w * 16 + mi;
    const ushort_t* rowp = mb + m * 1024;
    s16x8 r0 = *(const s16x8*)(rowp + lane * 8);
    s16x8 r1 = *(const s16x8*)(rowp + 512 + lane * 8);
    #pragma unroll
    for (int h = 0; h < 8; ++h){
      float acc = 0.f;
      #pragma unroll
      for (int e = 0; e < 8; ++e){
        acc += bf2f((ushort_t)r0[e]) * bf2f((ushort_t)qr0[h][e]);
        acc += bf2f((ushort_t)r1[e]) * bf2f((ushort_t)qr1[h][e]);
      }
      acc = wave_sum(acc);
      if (lane == 0) lg[h][m] = acc * 0.08838834764831845f; // 128^-0.5
    }
  }
  __syncthreads();
  #pragma unroll
  for (int hh = 0; hh < 2; ++hh){
    int h = w * 2 + hh;
    float v = lg[h][lane];
    float mx = wave_max(v);
    float e = __expf(v - mx);
    float s = wave_sum(e);
    at[h][lane] = e / s;
  }
  __syncthreads();
  #pragma unroll
  for (int jj = 0; jj < 4; ++jj){
    int j = tid + jj * 256;
    float acc[8] = {0.f,0.f,0.f,0.f,0.f,0.f,0.f,0.f};
    for (int m = 0; m < 64; ++m){
      float x = bf2f(mb[m * 1024 + j]);
      #pragma unroll
      for (int h = 0; h < 8; ++h) acc[h] += at[h][m] * x;
    }
    #pragma unroll
    for (int h = 0; h < 8; ++h)
      ctx[(size_t)b * 8192 + h * 1024 + j] = f2bf(acc[h]);
  }
}

// ---------- bf16 MFMA GEMM: C = [gelu](A @ Bt^T + bias) [+ R]; Bt is [N][K] ----------
#define GLL16(gsrc, ldst) \
  __builtin_amdgcn_global_load_lds((const __attribute__((address_space(1))) unsigned int*)(gsrc), \
                                   (__attribute__((address_space(3))) unsigned int*)(ldst), 16, 0, 0)

template<bool GELU, bool BIAS, bool WF32, bool WBF16, bool RESID>
__global__ __launch_bounds__(256, 2) void gemm_k(
    const ushort_t* __restrict__ A, int lda, long long aZ,
    const ushort_t* __restrict__ Bt, int ldb, long long bZ,
    const float* __restrict__ bias, long long biasZ,
    float* __restrict__ C, int ldc, long long cZ,
    ushort_t* __restrict__ Cb, int ldcb, long long cbZ,
    const float* __restrict__ R, int ldr,
    int M, int N, int K)
{
  __shared__ ushort_t smem[4][128 * 64];  // A0,A1,B0,B1 : 4 x 16KB
  int tid = threadIdx.x, lane = tid & 63, w = tid >> 6;
  int z = blockIdx.z;
  A  += (size_t)aZ * z;
  Bt += (size_t)bZ * z;
  if (BIAS)  bias += (size_t)biasZ * z;
  if (WF32)  C    += (size_t)cZ * z;
  if (WBF16) Cb   += (size_t)cbZ * z;
  int m0 = blockIdx.y * 128, n0 = blockIdx.x * 128;
  int nk = K >> 6;

  auto stage = [&](int buf, int kt){
    int k0 = kt << 6;
    #pragma unroll
    for (int i = 0; i < 4; ++i){
      int c = ((w << 2) + i) * 64 + lane;
      int rowl = c >> 3, sp = c & 7;
      int sg = sp ^ (rowl & 7);
      const ushort_t* srcA = A + (size_t)(m0 + rowl) * lda + (k0 + sg * 8);
      GLL16(srcA, &smem[buf][((w << 2) + i) * 512]);
    }
    #pragma unroll
    for (int i = 0; i < 4; ++i){
      int c = ((w << 2) + i) * 64 + lane;
      int rowl = c >> 3, sp = c & 7;
      int sg = sp ^ (rowl & 7);
      const ushort_t* srcB = Bt + (size_t)(n0 + rowl) * ldb + (k0 + sg * 8);
      GLL16(srcB, &smem[2 + buf][((w << 2) + i) * 512]);
    }
  };

  int qrow = w >> 1, qcol = w & 1;
  int l15 = lane & 15, lk = lane >> 4, l7 = lane & 7;
  int sb0 = ((0 + lk) ^ l7) << 4;   // byte slot offset within 128B row, kb=0
  int sb1 = ((4 + lk) ^ l7) << 4;   // kb=1
  int arow = (qrow * 64 + l15) * 128;  // byte base of this lane's A row
  int brow = (qcol * 64 + l15) * 128;

  f32x4 acc[4][4];
  #pragma unroll
  for (int m = 0; m < 4; ++m)
    #pragma unroll
    for (int n = 0; n < 4; ++n)
      acc[m][n] = (f32x4){0.f, 0.f, 0.f, 0.f};

  stage(0, 0);
  asm volatile("s_waitcnt vmcnt(0)" ::: "memory");
  __syncthreads();
  for (int kt = 0; kt < nk; ++kt){
    int cur = kt & 1;
    if (kt + 1 < nk) stage((kt + 1) & 1, kt + 1);
    const char* ab = (const char*)&smem[cur][0];
    const char* bb = (const char*)&smem[2 + cur][0];
    s16x8 af[4][2], bfv[4][2];
    #pragma unroll
    for (int m = 0; m < 4; ++m){
      af[m][0] = *(const s16x8*)(ab + arow + m * 2048 + sb0);
      af[m][1] = *(const s16x8*)(ab + arow + m * 2048 + sb1);
    }
    #pragma unroll
    for (int n = 0; n < 4; ++n){
      bfv[n][0] = *(const s16x8*)(bb + brow + n * 2048 + sb0);
      bfv[n][1] = *(const s16x8*)(bb + brow + n * 2048 + sb1);
    }
    #pragma unroll
    for (int kb = 0; kb < 2; ++kb)
      #pragma unroll
      for (int m = 0; m < 4; ++m)
        #pragma unroll
        for (int n = 0; n < 4; ++n)
          acc[m][n] = __builtin_amdgcn_mfma_f32_16x16x32_bf16(af[m][kb], bfv[n][kb], acc[m][n], 0, 0, 0);
    asm volatile("s_waitcnt vmcnt(0)" ::: "memory");
    __syncthreads();
  }

  #pragma unroll
  for (int n = 0; n < 4; ++n){
    int col = n0 + qcol * 64 + n * 16 + l15;
    float bvv = BIAS ? bias[col] : 0.0f;
    #pragma unroll
    for (int m = 0; m < 4; ++m){
      int rbase = m0 + qrow * 64 + m * 16 + lk * 4;
      #pragma unroll
      for (int r = 0; r < 4; ++r){
        float x = acc[m][n][r] + bvv;
        if (GELU) x = gelu_f(x);
        int row = rbase + r;
        if (RESID) x += R[(size_t)row * ldr + col];
        if (WF32)  C[(size_t)row * ldc + col] = x;
        if (WBF16) Cb[(size_t)row * ldcb + col] = f2bf(x);
      }
    }
  }
}

// ---------- host ----------
extern "C" void kernel_launch(void* const* d_in, const int* in_sizes, int n_in,
                              void* d_out, int out_size, void* d_ws, size_t ws_size,
                              hipStream_t stream)
{
  (void)in_sizes; (void)n_in; (void)out_size;
  const float* states      = (const float*)d_in[0];
  const float* time_values = (const float*)d_in[1];
  const float* class_sum   = (const float*)d_in[2];
  const float* support     = (const float*)d_in[3];
  const float* trunk_ln_g  = (const float*)d_in[4];
  const float* trunk_ln_b  = (const float*)d_in[5];
  const float* trunk_w1    = (const float*)d_in[6];
  const float* trunk_b1    = (const float*)d_in[7];
  const float* trunk_w2    = (const float*)d_in[8];
  const float* trunk_b2    = (const float*)d_in[9];
  const float* mem_ln_g    = (const float*)d_in[10];
  const float* mem_ln_b    = (const float*)d_in[11];
  const float* mem_w       = (const float*)d_in[12];
  const float* mem_b       = (const float*)d_in[13];
  const float* wq          = (const float*)d_in[14];
  const float* bq          = (const float*)d_in[15];
  const float* wk          = (const float*)d_in[16];
  /* d_in[17] = bk: provably unused (softmax shift invariance) */
  const float* wv          = (const float*)d_in[18];
  const float* bvp         = (const float*)d_in[19];
  const float* wo          = (const float*)d_in[20];
  const float* bo          = (const float*)d_in[21];
  const float* pre_g       = (const float*)d_in[22];
  const float* pre_b       = (const float*)d_in[23];
  const float* film_w      = (const float*)d_in[24];
  const float* film_b      = (const float*)d_in[25];
  const float* cond_g      = (const float*)d_in[26];
  const float* cond_b      = (const float*)d_in[27];
  const float* cond_w1     = (const float*)d_in[28];
  const float* cond_b1     = (const float*)d_in[29];
  const float* cond_w2     = (const float*)d_in[30];
  const float* cond_b2     = (const float*)d_in[31];
  const float* head_g      = (const float*)d_in[32];
  const float* head_bb     = (const float*)d_in[33];
  const float* head_w1     = (const float*)d_in[34];
  const float* head_b1     = (const float*)d_in[35];
  const float* head_w2     = (const float*)d_in[36];
  const float* head_b2     = (const float*)d_in[37];
  float* out = (float*)d_out;

  char* ws = (char*)d_ws;
  size_t off = 0;
  auto alloc = [&](size_t bytes)->char*{
    char* p = ws + off;
    off += (bytes + 255) & ~(size_t)255;
    return p;
  };
  // bf16 weights ([N][K] layout except wkB which is natural [j][c])
  ushort_t* tw1T   = (ushort_t*)alloc((size_t)640 * 1024 * 2);
  ushort_t* tw2T   = (ushort_t*)alloc((size_t)1024 * 1024 * 2);
  ushort_t* wqT    = (ushort_t*)alloc((size_t)1024 * 1024 * 2);
  ushort_t* wkB    = (ushort_t*)alloc((size_t)1024 * 1024 * 2);
  ushort_t* wvT    = (ushort_t*)alloc((size_t)1024 * 1024 * 2);
  ushort_t* woT    = (ushort_t*)alloc((size_t)1024 * 1024 * 2);
  ushort_t* memWT  = (ushort_t*)alloc((size_t)512 * 1024 * 2);
  ushort_t* filmWT = (ushort_t*)alloc((size_t)512 * 2048 * 2);
  ushort_t* cw1T   = (ushort_t*)alloc((size_t)1024 * 1024 * 2);
  ushort_t* cw2T   = (ushort_t*)alloc((size_t)1024 * 1024 * 2);
  ushort_t* hw1T   = (ushort_t*)alloc((size_t)1024 * 1024 * 2);
  ushort_t* hw2T   = (ushort_t*)alloc((size_t)1024 * 512 * 2);
  // activations
  ushort_t* xnb    = (ushort_t*)alloc((size_t)4096 * 640 * 2);
  ushort_t* h1     = (ushort_t*)alloc((size_t)4096 * 1024 * 2);
  float*    gf     = (float*)   alloc((size_t)4096 * 1024 * 4);
  ushort_t* gb     = (ushort_t*)alloc((size_t)4096 * 1024 * 2);
  ushort_t* qb     = (ushort_t*)alloc((size_t)4096 * 1024 * 2);
  ushort_t* qkb    = (ushort_t*)alloc((size_t)4096 * 8192 * 2);
  ushort_t* smn    = (ushort_t*)alloc((size_t)262144 * 512 * 2);
  ushort_t* memh   = (ushort_t*)alloc((size_t)262144 * 1024 * 2);
  ushort_t* ctxb   = (ushort_t*)alloc((size_t)4096 * 8192 * 2);
  ushort_t* sumb   = (ushort_t*)alloc((size_t)4096 * 1024 * 2);
  float*    asf    = (float*)   alloc((size_t)4096 * 1024 * 4);
  ushort_t* csb    = (ushort_t*)alloc((size_t)4096 * 512 * 2);
  float*    filmf  = (float*)   alloc((size_t)4096 * 2048 * 4);
  float*    c2f    = (float*)   alloc((size_t)4096 * 1024 * 4);
  ushort_t* cxb    = (ushort_t*)alloc((size_t)4096 * 1024 * 2);
  ushort_t* c1     = (ushort_t*)alloc((size_t)4096 * 1024 * 2);
  float*    cond2f = (float*)   alloc((size_t)4096 * 1024 * 4);
  ushort_t* hxb    = (ushort_t*)alloc((size_t)4096 * 1024 * 2);
  ushort_t* h3     = (ushort_t*)alloc((size_t)4096 * 1024 * 2);
  if (off > ws_size) return;  // workspace too small -> visible absmax failure

  dim3 tb(32, 8);
  // weight prep (runs per call; ~25MB total, negligible)
  transpose_cast_k<<<dim3(32, 20), tb, 0, stream>>>(trunk_w1, tw1T, 640, 1024);
  transpose_cast_k<<<dim3(32, 32), tb, 0, stream>>>(trunk_w2, tw2T, 1024, 1024);
  transpose_cast_k<<<dim3(32, 32), tb, 0, stream>>>(wq, wqT, 1024, 1024);
  transpose_cast_k<<<dim3(32, 32), tb, 0, stream>>>(wv, wvT, 1024, 1024);
  transpose_cast_k<<<dim3(32, 32), tb, 0, stream>>>(wo, woT, 1024, 1024);
  transpose_cast_k<<<dim3(32, 16), tb, 0, stream>>>(mem_w, memWT, 512, 1024);
  transpose_cast_k<<<dim3(64, 16), tb, 0, stream>>>(film_w, filmWT, 512, 2048);
  transpose_cast_k<<<dim3(32, 32), tb, 0, stream>>>(cond_w1, cw1T, 1024, 1024);
  transpose_cast_k<<<dim3(32, 32), tb, 0, stream>>>(cond_w2, cw2T, 1024, 1024);
  transpose_cast_k<<<dim3(32, 32), tb, 0, stream>>>(head_w1, hw1T, 1024, 1024);
  transpose_cast_k<<<dim3(16, 32), tb, 0, stream>>>(head_w2, hw2T, 1024, 512);
  cast4_k<<<1024, 256, 0, stream>>>(wk, wkB, 1024 * 1024);
  cast4_k<<<2048, 256, 0, stream>>>(class_sum, csb, 4096 * 512);

  // trunk
  ln_trunk_k<<<4096, 256, 0, stream>>>(states, time_values, trunk_ln_g, trunk_ln_b, xnb);
  gemm_k<true, true, false, true, false><<<dim3(8, 32, 1), 256, 0, stream>>>(
      xnb, 640, 0, tw1T, 640, 0, trunk_b1, 0, nullptr, 0, 0, h1, 1024, 0, nullptr, 0, 4096, 1024, 640);
  gemm_k<false, true, true, true, false><<<dim3(8, 32, 1), 256, 0, stream>>>(
      h1, 1024, 0, tw2T, 1024, 0, trunk_b2, 0, gf, 1024, 0, gb, 1024, 0, nullptr, 0, 4096, 1024, 1024);
  gemm_k<false, true, false, true, false><<<dim3(8, 32, 1), 256, 0, stream>>>(
      gb, 1024, 0, wqT, 1024, 0, bq, 0, nullptr, 0, 0, qb, 1024, 0, nullptr, 0, 4096, 1024, 1024);
  // qk[b,h,j] = sum_d q[b,h,d] * wk[j, h*128+d]   (per-head z-GEMM, K=128)
  gemm_k<false, false, false, true, false><<<dim3(8, 32, 8), 256, 0, stream>>>(
      qb, 1024, 128, wkB, 1024, 128, nullptr, 0, nullptr, 0, 0, qkb, 8192, 1024, nullptr, 0, 4096, 1024, 128);

  // memory path
  ln_mem_k<<<65536, 256, 0, stream>>>(support, mem_ln_g, mem_ln_b, smn);
  gemm_k<false, true, false, true, false><<<dim3(8, 2048, 1), 256, 0, stream>>>(
      smn, 512, 0, memWT, 512, 0, mem_b, 0, nullptr, 0, 0, memh, 1024, 0, nullptr, 0, 262144, 1024, 512);

  // attention (k/v never materialized)
  attn_k<<<4096, 256, 0, stream>>>(qkb, memh, ctxb);

  // summary_h = ctx_h @ wv[:, h-slice] + bv   (per-head z-GEMM, N=128)
  gemm_k<false, true, false, true, false><<<dim3(1, 32, 8), 256, 0, stream>>>(
      ctxb, 8192, 1024, wvT, 1024, 131072, bvp, 128, nullptr, 0, 0, sumb, 1024, 128, nullptr, 0, 4096, 128, 1024);
  gemm_k<false, true, true, false, false><<<dim3(8, 32, 1), 256, 0, stream>>>(
      sumb, 1024, 0, woT, 1024, 0, bo, 0, asf, 1024, 0, nullptr, 0, 0, nullptr, 0, 4096, 1024, 1024);
  gemm_k<false, true, true, false, false><<<dim3(16, 32, 1), 256, 0, stream>>>(
      csb, 512, 0, filmWT, 512, 0, film_b, 0, filmf, 2048, 0, nullptr, 0, 0, nullptr, 0, 4096, 2048, 512);

  fuse_film_k<<<4096, 256, 0, stream>>>(gf, asf, filmf, pre_g, pre_b, cond_g, cond_b, c2f, cxb);

  gemm_k<true, true, false, true, false><<<dim3(8, 32, 1), 256, 0, stream>>>(
      cxb, 1024, 0, cw1T, 1024, 0, cond_b1, 0, nullptr, 0, 0, c1, 1024, 0, nullptr, 0, 4096, 1024, 1024);
  gemm_k<false, true, true, false, true><<<dim3(8, 32, 1), 256, 0, stream>>>(
      c1, 1024, 0, cw2T, 1024, 0, cond_b2, 0, cond2f, 1024, 0, nullptr, 0, 0, c2f, 1024, 4096, 1024, 1024);
  ln_rows_k<<<4096, 256, 0, stream>>>(cond2f, head_g, head_bb, hxb, 1024);
  gemm_k<true, true, false, true, false><<<dim3(8, 32, 1), 256, 0, stream>>>(
      hxb, 1024, 0, hw1T, 1024, 0, head_b1, 0, nullptr, 0, 0, h3, 1024, 0, nullptr, 0, 4096, 1024, 1024);
  gemm_k<false, true, true, false, false><<<dim3(4, 32, 1), 256, 0, stream>>>(
      h3, 1024, 0, hw2T, 1024, 0, head_b2, 0, out, 512, 0, nullptr, 0, 0, nullptr, 0, 4096, 512, 1024);
}

// Round 2
// 682.015 us; speedup vs baseline: 1.9598x; 1.9598x over previous
//
#include <hip/hip_runtime.h>
#include <cstdint>
#include <cstddef>

typedef unsigned short ushort_t;
typedef short s16x8 __attribute__((ext_vector_type(8)));
typedef float f32x4 __attribute__((ext_vector_type(4)));

// ---------- small helpers ----------
__device__ __forceinline__ float bf2f(ushort_t h){
  union { unsigned int u; float f; } v; v.u = ((unsigned int)h) << 16; return v.f;
}
__device__ __forceinline__ ushort_t f2bf(float x){
  union { float f; unsigned int u; } v; v.f = x;
  unsigned int r = v.u + 0x7FFFu + ((v.u >> 16) & 1u);
  return (ushort_t)(r >> 16);
}
__device__ __forceinline__ float gelu_f(float x){
  return 0.5f * x * (1.0f + erff(x * 0.7071067811865475f));
}
__device__ __forceinline__ float wave_sum(float v){
  #pragma unroll
  for (int o = 32; o; o >>= 1) v += __shfl_xor(v, o);
  return v;
}
__device__ __forceinline__ float wave_max(float v){
  #pragma unroll
  for (int o = 32; o; o >>= 1) v = fmaxf(v, __shfl_xor(v, o));
  return v;
}
__device__ __forceinline__ void block_reduce2(float& s, float& q, float* red){
  s = wave_sum(s); q = wave_sum(q);
  int w = threadIdx.x >> 6, lane = threadIdx.x & 63, nw = blockDim.x >> 6;
  if (lane == 0){ red[w] = s; red[8 + w] = q; }
  __syncthreads();
  float ts = 0.f, tq = 0.f;
  for (int i = 0; i < nw; ++i){ ts += red[i]; tq += red[8 + i]; }
  __syncthreads();
  s = ts; q = tq;
}

// ---------- weight prep ----------
__global__ void transpose_cast_k(const float* __restrict__ in, ushort_t* __restrict__ out, int K, int N){
  __shared__ float t[32][33];
  int n0 = blockIdx.x * 32, k0 = blockIdx.y * 32;
  int tx = threadIdx.x, ty = threadIdx.y;
  #pragma unroll
  for (int j = 0; j < 32; j += 8){
    t[ty + j][tx] = in[(size_t)(k0 + ty + j) * N + (n0 + tx)];
  }
  __syncthreads();
  #pragma unroll
  for (int j = 0; j < 32; j += 8){
    out[(size_t)(n0 + ty + j) * K + (k0 + tx)] = f2bf(t[tx][ty + j]);
  }
}

__global__ void cast4_k(const float* __restrict__ in, ushort_t* __restrict__ out, int n){
  int i = (blockIdx.x * 256 + threadIdx.x) * 4;
  if (i >= n) return;
  float4 v = *(const float4*)(in + i);
  union { ushort_t u[4]; uint2 p; } pk;
  pk.u[0] = f2bf(v.x); pk.u[1] = f2bf(v.y); pk.u[2] = f2bf(v.z); pk.u[3] = f2bf(v.w);
  *(uint2*)(out + i) = pk.p;
}

// bv2 = mem_b @ wv + bv  (1024 outputs)
__global__ __launch_bounds__(128) void bv2_k(const float* __restrict__ mem_b, const float* __restrict__ wv,
                                             const float* __restrict__ bv, float* __restrict__ bv2){
  int col = blockIdx.x * 128 + threadIdx.x;
  float a0 = 0.f, a1 = 0.f, a2 = 0.f, a3 = 0.f;
  for (int j = 0; j < 1024; j += 4){
    a0 += mem_b[j + 0] * wv[(size_t)(j + 0) * 1024 + col];
    a1 += mem_b[j + 1] * wv[(size_t)(j + 1) * 1024 + col];
    a2 += mem_b[j + 2] * wv[(size_t)(j + 2) * 1024 + col];
    a3 += mem_b[j + 3] * wv[(size_t)(j + 3) * 1024 + col];
  }
  bv2[col] = a0 + a1 + a2 + a3 + bv[col];
}

// ---------- LN kernels ----------
__global__ __launch_bounds__(256) void ln_trunk_k(const float* __restrict__ states, const float* __restrict__ tv,
    const float* __restrict__ g, const float* __restrict__ b, ushort_t* __restrict__ out){
  int row = blockIdx.x, tid = threadIdx.x;
  __shared__ float buf[640];
  __shared__ float red[16];
  float t = tv[row];
  for (int i = tid; i < 640; i += 256){
    float v;
    if (i < 512) v = states[(size_t)row * 512 + i];
    else {
      int j = i - 512, jj = j & 63;
      float fr = expf(6.907755278982137f * ((float)jj * (1.0f / 63.0f)));
      float ang = 6.283185307179586f * t * fr;
      v = (j < 64) ? sinf(ang) : cosf(ang);
    }
    buf[i] = v;
  }
  __syncthreads();
  float s = 0.f, q = 0.f;
  for (int i = tid; i < 640; i += 256){ float v = buf[i]; s += v; q += v * v; }
  block_reduce2(s, q, red);
  float mean = s * (1.0f / 640.0f);
  float var = q * (1.0f / 640.0f) - mean * mean;
  float rstd = rsqrtf(var + 1e-5f);
  for (int i = tid; i < 640; i += 256)
    out[(size_t)row * 640 + i] = f2bf((buf[i] - mean) * rstd * g[i] + b[i]);
}

// generic row LN (D=1024, 4 elems/thread), f32 in -> bf16 out
__global__ __launch_bounds__(256) void ln_rows_k(const float* __restrict__ in, const float* __restrict__ g,
    const float* __restrict__ b, ushort_t* __restrict__ out, int D){
  int row = blockIdx.x, tid = threadIdx.x, i = tid * 4;
  __shared__ float red[16];
  const float* x = in + (size_t)row * D;
  float4 v = *(const float4*)(x + i);
  float s = v.x + v.y + v.z + v.w;
  float q = v.x * v.x + v.y * v.y + v.z * v.z + v.w * v.w;
  block_reduce2(s, q, red);
  float invD = 1.0f / (float)D;
  float mean = s * invD, var = q * invD - mean * mean, rstd = rsqrtf(var + 1e-5f);
  union { ushort_t u[4]; uint2 p; } pk;
  pk.u[0] = f2bf((v.x - mean) * rstd * g[i + 0] + b[i + 0]);
  pk.u[1] = f2bf((v.y - mean) * rstd * g[i + 1] + b[i + 1]);
  pk.u[2] = f2bf((v.z - mean) * rstd * g[i + 2] + b[i + 2]);
  pk.u[3] = f2bf((v.w - mean) * rstd * g[i + 3] + b[i + 3]);
  *(uint2*)(out + (size_t)row * D + i) = pk.p;
}

// combined = LN(g+as); c2 = (1+scale)*combined + shift; cx = LN(c2)
__global__ __launch_bounds__(256) void fuse_film_k(const float* __restrict__ gf, const float* __restrict__ asf,
    const float* __restrict__ film, const float* __restrict__ pg, const float* __restrict__ pb,
    const float* __restrict__ cg, const float* __restrict__ cb,
    float* __restrict__ c2f, ushort_t* __restrict__ cxb){
  int row = blockIdx.x, tid = threadIdx.x, i = tid * 4;
  __shared__ float red[16];
  float4 a = *(const float4*)(gf + (size_t)row * 1024 + i);
  float4 d = *(const float4*)(asf + (size_t)row * 1024 + i);
  float x[4] = { a.x + d.x, a.y + d.y, a.z + d.z, a.w + d.w };
  float s = x[0] + x[1] + x[2] + x[3];
  float q = x[0]*x[0] + x[1]*x[1] + x[2]*x[2] + x[3]*x[3];
  block_reduce2(s, q, red);
  float mean = s * (1.0f / 1024.0f), var = q * (1.0f / 1024.0f) - mean * mean;
  float rstd = rsqrtf(var + 1e-5f);
  float4 pgv = *(const float4*)(pg + i), pbv = *(const float4*)(pb + i);
  float4 sc = *(const float4*)(film + (size_t)row * 2048 + i);
  float4 sh = *(const float4*)(film + (size_t)row * 2048 + 1024 + i);
  float c2[4];
  {
    float pgx[4] = { pgv.x, pgv.y, pgv.z, pgv.w };
    float pbx[4] = { pbv.x, pbv.y, pbv.z, pbv.w };
    float scx[4] = { sc.x, sc.y, sc.z, sc.w };
    float shx[4] = { sh.x, sh.y, sh.z, sh.w };
    #pragma unroll
    for (int e = 0; e < 4; ++e){
      float cc = (x[e] - mean) * rstd * pgx[e] + pbx[e];
      c2[e] = (1.0f + scx[e]) * cc + shx[e];
    }
  }
  *(float4*)(c2f + (size_t)row * 1024 + i) = make_float4(c2[0], c2[1], c2[2], c2[3]);
  float s2 = c2[0] + c2[1] + c2[2] + c2[3];
  float q2 = c2[0]*c2[0] + c2[1]*c2[1] + c2[2]*c2[2] + c2[3]*c2[3];
  block_reduce2(s2, q2, red);
  float m2 = s2 * (1.0f / 1024.0f), v2 = q2 * (1.0f / 1024.0f) - m2 * m2;
  float r2 = rsqrtf(v2 + 1e-5f);
  float4 cgv = *(const float4*)(cg + i), cbv = *(const float4*)(cb + i);
  union { ushort_t u[4]; uint2 p; } pk;
  pk.u[0] = f2bf((c2[0] - m2) * r2 * cgv.x + cbv.x);
  pk.u[1] = f2bf((c2[1] - m2) * r2 * cgv.y + cbv.y);
  pk.u[2] = f2bf((c2[2] - m2) * r2 * cgv.z + cbv.z);
  pk.u[3] = f2bf((c2[3] - m2) * r2 * cgv.w + cbv.w);
  *(uint2*)(cxb + (size_t)row * 1024 + i) = pk.p;
}

// ---------- fused support path: LN + logits + softmax + r, one block per b ----------
// logits[h,m] = SCALE * sum_c S[m,c]*u[b,h,c];  r[b,h,c] = sum_m attn[h,m]*S[m,c]
__global__ __launch_bounds__(256) void suppattn_k(
    const float* __restrict__ support, const float* __restrict__ lgw, const float* __restrict__ lbw,
    const ushort_t* __restrict__ U, ushort_t* __restrict__ R)
{
  __shared__ ushort_t S[64 * 512];   // 64 KB
  __shared__ float lg[8][64];
  __shared__ float at[8][64];
  int bb = blockIdx.x, tid = threadIdx.x, w = tid >> 6, l = tid & 63;
  float gg[8], bb8[8];
  #pragma unroll
  for (int e = 0; e < 8; ++e){ gg[e] = lgw[l * 8 + e]; bb8[e] = lbw[l * 8 + e]; }
  const ushort_t* Ub = U + (size_t)bb * 4096;
  float uf[8][8];
  #pragma unroll
  for (int h = 0; h < 8; ++h){
    s16x8 ur = *(const s16x8*)(Ub + h * 512 + l * 8);
    #pragma unroll
    for (int e = 0; e < 8; ++e) uf[h][e] = bf2f((ushort_t)ur[e]);
  }
  for (int mi = 0; mi < 16; ++mi){
    int m = w * 16 + mi;
    const float* row = support + ((size_t)bb * 64 + m) * 512 + l * 8;
    float4 a0 = *(const float4*)row;
    float4 a1 = *(const float4*)(row + 4);
    float v[8] = { a0.x, a0.y, a0.z, a0.w, a1.x, a1.y, a1.z, a1.w };
    float s = 0.f, q = 0.f;
    #pragma unroll
    for (int e = 0; e < 8; ++e){ s += v[e]; q += v[e] * v[e]; }
    s = wave_sum(s); q = wave_sum(q);
    float mean = s * (1.0f / 512.0f);
    float var = q * (1.0f / 512.0f) - mean * mean;
    float rstd = rsqrtf(var + 1e-5f);
    float sn[8];
    union { ushort_t u[8]; uint4 p4; } pk;
    #pragma unroll
    for (int e = 0; e < 8; ++e){ sn[e] = (v[e] - mean) * rstd * gg[e] + bb8[e]; pk.u[e] = f2bf(sn[e]); }
    *(uint4*)(&S[m * 512 + l * 8]) = pk.p4;
    float p[8];
    #pragma unroll
    for (int h = 0; h < 8; ++h){
      float acc = 0.f;
      #pragma unroll
      for (int e = 0; e < 8; ++e) acc += sn[e] * uf[h][e];
      p[h] = acc;
    }
    #pragma unroll
    for (int h = 0; h < 8; ++h) p[h] = wave_sum(p[h]);
    if (l == 0){
      #pragma unroll
      for (int h = 0; h < 8; ++h) lg[h][m] = p[h] * 0.08838834764831845f;
    }
  }
  __syncthreads();
  #pragma unroll
  for (int hh = 0; hh < 2; ++hh){
    int h = w * 2 + hh;
    float vv = lg[h][l];
    float mx = wave_max(vv);
    float e = __expf(vv - mx);
    float sm = wave_sum(e);
    at[h][l] = e / sm;
  }
  __syncthreads();
  #pragma unroll
  for (int cc = 0; cc < 2; ++cc){
    int c = tid + cc * 256;
    float acc[8] = {0.f,0.f,0.f,0.f,0.f,0.f,0.f,0.f};
    for (int m = 0; m < 64; ++m){
      float sv = bf2f(S[m * 512 + c]);
      #pragma unroll
      for (int h = 0; h < 8; ++h) acc[h] += at[h][m] * sv;
    }
    #pragma unroll
    for (int h = 0; h < 8; ++h)
      R[(size_t)bb * 4096 + h * 512 + c] = f2bf(acc[h]);
  }
}

// ---------- bf16 MFMA GEMM: C = [gelu](A @ Bt^T + bias) [+ R]; Bt is [N][K] ----------
#define GLL16(gsrc, ldst) \
  __builtin_amdgcn_global_load_lds((const __attribute__((address_space(1))) unsigned int*)(gsrc), \
                                   (__attribute__((address_space(3))) unsigned int*)(ldst), 16, 0, 0)

template<bool GELU, bool BIAS, bool WF32, bool WBF16, bool RESID>
__global__ __launch_bounds__(256, 2) void gemm_k(
    const ushort_t* __restrict__ A, int lda, long long aZ,
    const ushort_t* __restrict__ Bt, int ldb, long long bZ,
    const float* __restrict__ bias, long long biasZ,
    float* __restrict__ C, int ldc, long long cZ,
    ushort_t* __restrict__ Cb, int ldcb, long long cbZ,
    const float* __restrict__ R, int ldr,
    int M, int N, int K)
{
  __shared__ ushort_t smem[4][128 * 64];  // A0,A1,B0,B1 : 4 x 16KB
  int tid = threadIdx.x, lane = tid & 63, w = tid >> 6;
  int z = blockIdx.z;
  A  += (size_t)aZ * z;
  Bt += (size_t)bZ * z;
  if (BIAS)  bias += (size_t)biasZ * z;
  if (WF32)  C    += (size_t)cZ * z;
  if (WBF16) Cb   += (size_t)cbZ * z;
  int m0 = blockIdx.y * 128, n0 = blockIdx.x * 128;
  int nk = K >> 6;

  auto stage = [&](int buf, int kt){
    int k0 = kt << 6;
    #pragma unroll
    for (int i = 0; i < 4; ++i){
      int c = ((w << 2) + i) * 64 + lane;
      int rowl = c >> 3, sp = c & 7;
      int sg = sp ^ (rowl & 7);
      const ushort_t* srcA = A + (size_t)(m0 + rowl) * lda + (k0 + sg * 8);
      GLL16(srcA, &smem[buf][((w << 2) + i) * 512]);
    }
    #pragma unroll
    for (int i = 0; i < 4; ++i){
      int c = ((w << 2) + i) * 64 + lane;
      int rowl = c >> 3, sp = c & 7;
      int sg = sp ^ (rowl & 7);
      const ushort_t* srcB = Bt + (size_t)(n0 + rowl) * ldb + (k0 + sg * 8);
      GLL16(srcB, &smem[2 + buf][((w << 2) + i) * 512]);
    }
  };

  int qrow = w >> 1, qcol = w & 1;
  int l15 = lane & 15, lk = lane >> 4, l7 = lane & 7;
  int sb0 = ((0 + lk) ^ l7) << 4;
  int sb1 = ((4 + lk) ^ l7) << 4;
  int arow = (qrow * 64 + l15) * 128;
  int brow = (qcol * 64 + l15) * 128;

  f32x4 acc[4][4];
  #pragma unroll
  for (int m = 0; m < 4; ++m)
    #pragma unroll
    for (int n = 0; n < 4; ++n)
      acc[m][n] = (f32x4){0.f, 0.f, 0.f, 0.f};

  stage(0, 0);
  asm volatile("s_waitcnt vmcnt(0)" ::: "memory");
  __syncthreads();
  for (int kt = 0; kt < nk; ++kt){
    int cur = kt & 1;
    if (kt + 1 < nk) stage((kt + 1) & 1, kt + 1);
    const char* ab = (const char*)&smem[cur][0];
    const char* bb = (const char*)&smem[2 + cur][0];
    s16x8 af[4][2], bfv[4][2];
    #pragma unroll
    for (int m = 0; m < 4; ++m){
      af[m][0] = *(const s16x8*)(ab + arow + m * 2048 + sb0);
      af[m][1] = *(const s16x8*)(ab + arow + m * 2048 + sb1);
    }
    #pragma unroll
    for (int n = 0; n < 4; ++n){
      bfv[n][0] = *(const s16x8*)(bb + brow + n * 2048 + sb0);
      bfv[n][1] = *(const s16x8*)(bb + brow + n * 2048 + sb1);
    }
    #pragma unroll
    for (int kb = 0; kb < 2; ++kb)
      #pragma unroll
      for (int m = 0; m < 4; ++m)
        #pragma unroll
        for (int n = 0; n < 4; ++n)
          acc[m][n] = __builtin_amdgcn_mfma_f32_16x16x32_bf16(af[m][kb], bfv[n][kb], acc[m][n], 0, 0, 0);
    asm volatile("s_waitcnt vmcnt(0)" ::: "memory");
    __syncthreads();
  }

  #pragma unroll
  for (int n = 0; n < 4; ++n){
    int col = n0 + qcol * 64 + n * 16 + l15;
    float bvv = BIAS ? bias[col] : 0.0f;
    #pragma unroll
    for (int m = 0; m < 4; ++m){
      int rbase = m0 + qrow * 64 + m * 16 + lk * 4;
      #pragma unroll
      for (int r = 0; r < 4; ++r){
        float x = acc[m][n][r] + bvv;
        if (GELU) x = gelu_f(x);
        int row = rbase + r;
        if (RESID) x += R[(size_t)row * ldr + col];
        if (WF32)  C[(size_t)row * ldc + col] = x;
        if (WBF16) Cb[(size_t)row * ldcb + col] = f2bf(x);
      }
    }
  }
}

// ---------- host ----------
extern "C" void kernel_launch(void* const* d_in, const int* in_sizes, int n_in,
                              void* d_out, int out_size, void* d_ws, size_t ws_size,
                              hipStream_t stream)
{
  (void)in_sizes; (void)n_in; (void)out_size;
  const float* states      = (const float*)d_in[0];
  const float* time_values = (const float*)d_in[1];
  const float* class_sum   = (const float*)d_in[2];
  const float* support     = (const float*)d_in[3];
  const float* trunk_ln_g  = (const float*)d_in[4];
  const float* trunk_ln_b  = (const float*)d_in[5];
  const float* trunk_w1    = (const float*)d_in[6];
  const float* trunk_b1    = (const float*)d_in[7];
  const float* trunk_w2    = (const float*)d_in[8];
  const float* trunk_b2    = (const float*)d_in[9];
  const float* mem_ln_g    = (const float*)d_in[10];
  const float* mem_ln_b    = (const float*)d_in[11];
  const float* mem_w       = (const float*)d_in[12];
  const float* mem_b       = (const float*)d_in[13];
  const float* wq          = (const float*)d_in[14];
  const float* bq          = (const float*)d_in[15];
  const float* wk          = (const float*)d_in[16];
  /* d_in[17] = bk: unused (softmax shift invariance) */
  const float* wv          = (const float*)d_in[18];
  const float* bvp         = (const float*)d_in[19];
  const float* wo          = (const float*)d_in[20];
  const float* bo          = (const float*)d_in[21];
  const float* pre_g       = (const float*)d_in[22];
  const float* pre_b       = (const float*)d_in[23];
  const float* film_w      = (const float*)d_in[24];
  const float* film_b      = (const float*)d_in[25];
  const float* cond_g      = (const float*)d_in[26];
  const float* cond_b      = (const float*)d_in[27];
  const float* cond_w1     = (const float*)d_in[28];
  const float* cond_b1     = (const float*)d_in[29];
  const float* cond_w2     = (const float*)d_in[30];
  const float* cond_b2     = (const float*)d_in[31];
  const float* head_g      = (const float*)d_in[32];
  const float* head_bb     = (const float*)d_in[33];
  const float* head_w1     = (const float*)d_in[34];
  const float* head_b1     = (const float*)d_in[35];
  const float* head_w2     = (const float*)d_in[36];
  const float* head_b2     = (const float*)d_in[37];
  float* out = (float*)d_out;

  char* ws = (char*)d_ws;
  size_t off = 0;
  auto alloc = [&](size_t bytes)->char*{
    char* p = ws + off;
    off += (bytes + 255) & ~(size_t)255;
    return p;
  };
  // bf16 weights
  ushort_t* tw1T   = (ushort_t*)alloc((size_t)640 * 1024 * 2);
  ushort_t* tw2T   = (ushort_t*)alloc((size_t)1024 * 1024 * 2);
  ushort_t* wqT    = (ushort_t*)alloc((size_t)1024 * 1024 * 2);
  ushort_t* wkT    = (ushort_t*)alloc((size_t)1024 * 1024 * 2);
  ushort_t* wvT    = (ushort_t*)alloc((size_t)1024 * 1024 * 2);
  ushort_t* woT    = (ushort_t*)alloc((size_t)1024 * 1024 * 2);
  ushort_t* memw_b = (ushort_t*)alloc((size_t)512 * 1024 * 2);   // natural [c][j]
  ushort_t* filmWT = (ushort_t*)alloc((size_t)512 * 2048 * 2);
  ushort_t* cw1T   = (ushort_t*)alloc((size_t)1024 * 1024 * 2);
  ushort_t* cw2T   = (ushort_t*)alloc((size_t)1024 * 1024 * 2);
  ushort_t* hw1T   = (ushort_t*)alloc((size_t)1024 * 1024 * 2);
  ushort_t* hw2T   = (ushort_t*)alloc((size_t)1024 * 512 * 2);
  ushort_t* K2     = (ushort_t*)alloc((size_t)512 * 1024 * 2);   // [c][hd] = mem_w @ wk
  ushort_t* V2T    = (ushort_t*)alloc((size_t)1024 * 512 * 2);   // [hd][c] = (mem_w @ wv)^T
  float*    bv2    = (float*)   alloc((size_t)1024 * 4);
  // activations
  ushort_t* xnb    = (ushort_t*)alloc((size_t)4096 * 640 * 2);
  ushort_t* h1     = (ushort_t*)alloc((size_t)4096 * 1024 * 2);
  float*    gf     = (float*)   alloc((size_t)4096 * 1024 * 4);
  ushort_t* gb     = (ushort_t*)alloc((size_t)4096 * 1024 * 2);
  ushort_t* qb     = (ushort_t*)alloc((size_t)4096 * 1024 * 2);
  ushort_t* U      = (ushort_t*)alloc((size_t)4096 * 4096 * 2);  // [b][h][c]
  ushort_t* Rb     = (ushort_t*)alloc((size_t)4096 * 4096 * 2);  // [b][h][c]
  ushort_t* sumb   = (ushort_t*)alloc((size_t)4096 * 1024 * 2);
  float*    asf    = (float*)   alloc((size_t)4096 * 1024 * 4);
  ushort_t* csb    = (ushort_t*)alloc((size_t)4096 * 512 * 2);
  float*    filmf  = (float*)   alloc((size_t)4096 * 2048 * 4);
  float*    c2f    = (float*)   alloc((size_t)4096 * 1024 * 4);
  ushort_t* cxb    = (ushort_t*)alloc((size_t)4096 * 1024 * 2);
  ushort_t* c1     = (ushort_t*)alloc((size_t)4096 * 1024 * 2);
  float*    cond2f = (float*)   alloc((size_t)4096 * 1024 * 4);
  ushort_t* hxb    = (ushort_t*)alloc((size_t)4096 * 1024 * 2);
  ushort_t* h3     = (ushort_t*)alloc((size_t)4096 * 1024 * 2);
  if (off > ws_size) return;

  dim3 tb(32, 8);
  // weight prep
  transpose_cast_k<<<dim3(32, 20), tb, 0, stream>>>(trunk_w1, tw1T, 640, 1024);
  transpose_cast_k<<<dim3(32, 32), tb, 0, stream>>>(trunk_w2, tw2T, 1024, 1024);
  transpose_cast_k<<<dim3(32, 32), tb, 0, stream>>>(wq, wqT, 1024, 1024);
  transpose_cast_k<<<dim3(32, 32), tb, 0, stream>>>(wk, wkT, 1024, 1024);
  transpose_cast_k<<<dim3(32, 32), tb, 0, stream>>>(wv, wvT, 1024, 1024);
  transpose_cast_k<<<dim3(32, 32), tb, 0, stream>>>(wo, woT, 1024, 1024);
  transpose_cast_k<<<dim3(64, 16), tb, 0, stream>>>(film_w, filmWT, 512, 2048);
  transpose_cast_k<<<dim3(32, 32), tb, 0, stream>>>(cond_w1, cw1T, 1024, 1024);
  transpose_cast_k<<<dim3(32, 32), tb, 0, stream>>>(cond_w2, cw2T, 1024, 1024);
  transpose_cast_k<<<dim3(32, 32), tb, 0, stream>>>(head_w1, hw1T, 1024, 1024);
  transpose_cast_k<<<dim3(16, 32), tb, 0, stream>>>(head_w2, hw2T, 1024, 512);
  cast4_k<<<512, 256, 0, stream>>>(mem_w, memw_b, 512 * 1024);
  cast4_k<<<2048, 256, 0, stream>>>(class_sum, csb, 4096 * 512);
  bv2_k<<<8, 128, 0, stream>>>(mem_b, wv, bvp, bv2);

  // weight-weight products: K2[c][hd] = sum_j mem_w[c][j]*wk[j][hd]; V2T[hd][c] = sum_j wv[j][hd]*mem_w[c][j]
  gemm_k<false, false, false, true, false><<<dim3(8, 4, 1), 256, 0, stream>>>(
      memw_b, 1024, 0, wkT, 1024, 0, nullptr, 0, nullptr, 0, 0, K2, 1024, 0, nullptr, 0, 512, 1024, 1024);
  gemm_k<false, false, false, true, false><<<dim3(4, 8, 1), 256, 0, stream>>>(
      wvT, 1024, 0, memw_b, 1024, 0, nullptr, 0, nullptr, 0, 0, V2T, 512, 0, nullptr, 0, 1024, 512, 1024);

  // trunk
  ln_trunk_k<<<4096, 256, 0, stream>>>(states, time_values, trunk_ln_g, trunk_ln_b, xnb);
  gemm_k<true, true, false, true, false><<<dim3(8, 32, 1), 256, 0, stream>>>(
      xnb, 640, 0, tw1T, 640, 0, trunk_b1, 0, nullptr, 0, 0, h1, 1024, 0, nullptr, 0, 4096, 1024, 640);
  gemm_k<false, true, true, true, false><<<dim3(8, 32, 1), 256, 0, stream>>>(
      h1, 1024, 0, tw2T, 1024, 0, trunk_b2, 0, gf, 1024, 0, gb, 1024, 0, nullptr, 0, 4096, 1024, 1024);
  gemm_k<false, true, false, true, false><<<dim3(8, 32, 1), 256, 0, stream>>>(
      gb, 1024, 0, wqT, 1024, 0, bq, 0, nullptr, 0, 0, qb, 1024, 0, nullptr, 0, 4096, 1024, 1024);
  // U[b][h*512+c] = sum_d q[b][h*128+d] * K2[c][h*128+d]   (per-head z-GEMM, K=128)
  gemm_k<false, false, false, true, false><<<dim3(4, 32, 8), 256, 0, stream>>>(
      qb, 1024, 128, K2, 1024, 128, nullptr, 0, nullptr, 0, 0, U, 4096, 512, nullptr, 0, 4096, 512, 128);

  // fused support path (LN + logits + softmax + r); memh never materialized
  suppattn_k<<<4096, 256, 0, stream>>>(support, mem_ln_g, mem_ln_b, U, Rb);

  // summary[b][h*128+d] = sum_c R[b][h*512+c] * V2T[h*128+d][c] + bv2[h*128+d]
  gemm_k<false, true, false, true, false><<<dim3(1, 32, 8), 256, 0, stream>>>(
      Rb, 4096, 512, V2T, 512, 65536, bv2, 128, nullptr, 0, 0, sumb, 1024, 128, nullptr, 0, 4096, 128, 512);

  gemm_k<false, true, true, false, false><<<dim3(8, 32, 1), 256, 0, stream>>>(
      sumb, 1024, 0, woT, 1024, 0, bo, 0, asf, 1024, 0, nullptr, 0, 0, nullptr, 0, 4096, 1024, 1024);
  gemm_k<false, true, true, false, false><<<dim3(16, 32, 1), 256, 0, stream>>>(
      csb, 512, 0, filmWT, 512, 0, film_b, 0, filmf, 2048, 0, nullptr, 0, 0, nullptr, 0, 4096, 2048, 512);

  fuse_film_k<<<4096, 256, 0, stream>>>(gf, asf, filmf, pre_g, pre_b, cond_g, cond_b, c2f, cxb);

  gemm_k<true, true, false, true, false><<<dim3(8, 32, 1), 256, 0, stream>>>(
      cxb, 1024, 0, cw1T, 1024, 0, cond_b1, 0, nullptr, 0, 0, c1, 1024, 0, nullptr, 0, 4096, 1024, 1024);
  gemm_k<false, true, true, false, true><<<dim3(8, 32, 1), 256, 0, stream>>>(
      c1, 1024, 0, cw2T, 1024, 0, cond_b2, 0, cond2f, 1024, 0, nullptr, 0, 0, c2f, 1024, 4096, 1024, 1024);
  ln_rows_k<<<4096, 256, 0, stream>>>(cond2f, head_g, head_bb, hxb, 1024);
  gemm_k<true, true, false, true, false><<<dim3(8, 32, 1), 256, 0, stream>>>(
      hxb, 1024, 0, hw1T, 1024, 0, head_b1, 0, nullptr, 0, 0, h3, 1024, 0, nullptr, 0, 4096, 1024, 1024);
  gemm_k<false, true, true, false, false><<<dim3(4, 32, 1), 256, 0, stream>>>(
      h3, 1024, 0, hw2T, 1024, 0, head_b2, 0, out, 512, 0, nullptr, 0, 0, nullptr, 0, 4096, 512, 1024);
}

// Round 3
// 574.017 us; speedup vs baseline: 2.3285x; 1.1881x over previous
//
#include <hip/hip_runtime.h>
#include <cstdint>
#include <cstddef>

typedef unsigned short ushort_t;
typedef short s16x8 __attribute__((ext_vector_type(8)));
typedef float f32x4 __attribute__((ext_vector_type(4)));

// ---------- small helpers ----------
__device__ __forceinline__ float bf2f(ushort_t h){
  union { unsigned int u; float f; } v; v.u = ((unsigned int)h) << 16; return v.f;
}
__device__ __forceinline__ ushort_t f2bf(float x){
  union { float f; unsigned int u; } v; v.f = x;
  unsigned int r = v.u + 0x7FFFu + ((v.u >> 16) & 1u);
  return (ushort_t)(r >> 16);
}
__device__ __forceinline__ float gelu_f(float x){
  return 0.5f * x * (1.0f + erff(x * 0.7071067811865475f));
}
__device__ __forceinline__ float wave_sum(float v){
  #pragma unroll
  for (int o = 32; o; o >>= 1) v += __shfl_xor(v, o);
  return v;
}
__device__ __forceinline__ void block_reduce2(float& s, float& q, float* red){
  s = wave_sum(s); q = wave_sum(q);
  int w = threadIdx.x >> 6, lane = threadIdx.x & 63, nw = blockDim.x >> 6;
  if (lane == 0){ red[w] = s; red[8 + w] = q; }
  __syncthreads();
  float ts = 0.f, tq = 0.f;
  for (int i = 0; i < nw; ++i){ ts += red[i]; tq += red[8 + i]; }
  __syncthreads();
  s = ts; q = tq;
}

// ---------- weight prep ----------
__global__ void transpose_cast_k(const float* __restrict__ in, ushort_t* __restrict__ out, int K, int N){
  __shared__ float t[32][33];
  int n0 = blockIdx.x * 32, k0 = blockIdx.y * 32;
  int tx = threadIdx.x, ty = threadIdx.y;
  #pragma unroll
  for (int j = 0; j < 32; j += 8){
    t[ty + j][tx] = in[(size_t)(k0 + ty + j) * N + (n0 + tx)];
  }
  __syncthreads();
  #pragma unroll
  for (int j = 0; j < 32; j += 8){
    out[(size_t)(n0 + ty + j) * K + (k0 + tx)] = f2bf(t[tx][ty + j]);
  }
}

__global__ void cast4_k(const float* __restrict__ in, ushort_t* __restrict__ out, int n){
  int i = (blockIdx.x * 256 + threadIdx.x) * 4;
  if (i >= n) return;
  float4 v = *(const float4*)(in + i);
  union { ushort_t u[4]; uint2 p; } pk;
  pk.u[0] = f2bf(v.x); pk.u[1] = f2bf(v.y); pk.u[2] = f2bf(v.z); pk.u[3] = f2bf(v.w);
  *(uint2*)(out + i) = pk.p;
}

// bv2 = mem_b @ wv + bv  (1024 outputs)
__global__ __launch_bounds__(128) void bv2_k(const float* __restrict__ mem_b, const float* __restrict__ wv,
                                             const float* __restrict__ bv, float* __restrict__ bv2){
  int col = blockIdx.x * 128 + threadIdx.x;
  float a0 = 0.f, a1 = 0.f, a2 = 0.f, a3 = 0.f;
  for (int j = 0; j < 1024; j += 4){
    a0 += mem_b[j + 0] * wv[(size_t)(j + 0) * 1024 + col];
    a1 += mem_b[j + 1] * wv[(size_t)(j + 1) * 1024 + col];
    a2 += mem_b[j + 2] * wv[(size_t)(j + 2) * 1024 + col];
    a3 += mem_b[j + 3] * wv[(size_t)(j + 3) * 1024 + col];
  }
  bv2[col] = a0 + a1 + a2 + a3 + bv[col];
}

// ---------- LN kernels ----------
__global__ __launch_bounds__(256) void ln_trunk_k(const float* __restrict__ states, const float* __restrict__ tv,
    const float* __restrict__ g, const float* __restrict__ b, ushort_t* __restrict__ out){
  int row = blockIdx.x, tid = threadIdx.x;
  __shared__ float buf[640];
  __shared__ float red[16];
  float t = tv[row];
  for (int i = tid; i < 640; i += 256){
    float v;
    if (i < 512) v = states[(size_t)row * 512 + i];
    else {
      int j = i - 512, jj = j & 63;
      float fr = expf(6.907755278982137f * ((float)jj * (1.0f / 63.0f)));
      float ang = 6.283185307179586f * t * fr;
      v = (j < 64) ? sinf(ang) : cosf(ang);
    }
    buf[i] = v;
  }
  __syncthreads();
  float s = 0.f, q = 0.f;
  for (int i = tid; i < 640; i += 256){ float v = buf[i]; s += v; q += v * v; }
  block_reduce2(s, q, red);
  float mean = s * (1.0f / 640.0f);
  float var = q * (1.0f / 640.0f) - mean * mean;
  float rstd = rsqrtf(var + 1e-5f);
  for (int i = tid; i < 640; i += 256)
    out[(size_t)row * 640 + i] = f2bf((buf[i] - mean) * rstd * g[i] + b[i]);
}

// generic row LN (D=1024, 4 elems/thread), f32 in -> bf16 out
__global__ __launch_bounds__(256) void ln_rows_k(const float* __restrict__ in, const float* __restrict__ g,
    const float* __restrict__ b, ushort_t* __restrict__ out, int D){
  int row = blockIdx.x, tid = threadIdx.x, i = tid * 4;
  __shared__ float red[16];
  const float* x = in + (size_t)row * D;
  float4 v = *(const float4*)(x + i);
  float s = v.x + v.y + v.z + v.w;
  float q = v.x * v.x + v.y * v.y + v.z * v.z + v.w * v.w;
  block_reduce2(s, q, red);
  float invD = 1.0f / (float)D;
  float mean = s * invD, var = q * invD - mean * mean, rstd = rsqrtf(var + 1e-5f);
  union { ushort_t u[4]; uint2 p; } pk;
  pk.u[0] = f2bf((v.x - mean) * rstd * g[i + 0] + b[i + 0]);
  pk.u[1] = f2bf((v.y - mean) * rstd * g[i + 1] + b[i + 1]);
  pk.u[2] = f2bf((v.z - mean) * rstd * g[i + 2] + b[i + 2]);
  pk.u[3] = f2bf((v.w - mean) * rstd * g[i + 3] + b[i + 3]);
  *(uint2*)(out + (size_t)row * D + i) = pk.p;
}

// combined = LN(g+as); c2 = (1+scale)*combined + shift; cx = LN(c2)
__global__ __launch_bounds__(256) void fuse_film_k(const float* __restrict__ gf, const float* __restrict__ asf,
    const float* __restrict__ film, const float* __restrict__ pg, const float* __restrict__ pb,
    const float* __restrict__ cg, const float* __restrict__ cb,
    float* __restrict__ c2f, ushort_t* __restrict__ cxb){
  int row = blockIdx.x, tid = threadIdx.x, i = tid * 4;
  __shared__ float red[16];
  float4 a = *(const float4*)(gf + (size_t)row * 1024 + i);
  float4 d = *(const float4*)(asf + (size_t)row * 1024 + i);
  float x[4] = { a.x + d.x, a.y + d.y, a.z + d.z, a.w + d.w };
  float s = x[0] + x[1] + x[2] + x[3];
  float q = x[0]*x[0] + x[1]*x[1] + x[2]*x[2] + x[3]*x[3];
  block_reduce2(s, q, red);
  float mean = s * (1.0f / 1024.0f), var = q * (1.0f / 1024.0f) - mean * mean;
  float rstd = rsqrtf(var + 1e-5f);
  float4 pgv = *(const float4*)(pg + i), pbv = *(const float4*)(pb + i);
  float4 sc = *(const float4*)(film + (size_t)row * 2048 + i);
  float4 sh = *(const float4*)(film + (size_t)row * 2048 + 1024 + i);
  float c2[4];
  {
    float pgx[4] = { pgv.x, pgv.y, pgv.z, pgv.w };
    float pbx[4] = { pbv.x, pbv.y, pbv.z, pbv.w };
    float scx[4] = { sc.x, sc.y, sc.z, sc.w };
    float shx[4] = { sh.x, sh.y, sh.z, sh.w };
    #pragma unroll
    for (int e = 0; e < 4; ++e){
      float cc = (x[e] - mean) * rstd * pgx[e] + pbx[e];
      c2[e] = (1.0f + scx[e]) * cc + shx[e];
    }
  }
  *(float4*)(c2f + (size_t)row * 1024 + i) = make_float4(c2[0], c2[1], c2[2], c2[3]);
  float s2 = c2[0] + c2[1] + c2[2] + c2[3];
  float q2 = c2[0]*c2[0] + c2[1]*c2[1] + c2[2]*c2[2] + c2[3]*c2[3];
  block_reduce2(s2, q2, red);
  float m2 = s2 * (1.0f / 1024.0f), v2 = q2 * (1.0f / 1024.0f) - m2 * m2;
  float r2 = rsqrtf(v2 + 1e-5f);
  float4 cgv = *(const float4*)(cg + i), cbv = *(const float4*)(cb + i);
  union { ushort_t u[4]; uint2 p; } pk;
  pk.u[0] = f2bf((c2[0] - m2) * r2 * cgv.x + cbv.x);
  pk.u[1] = f2bf((c2[1] - m2) * r2 * cgv.y + cbv.y);
  pk.u[2] = f2bf((c2[2] - m2) * r2 * cgv.z + cbv.z);
  pk.u[3] = f2bf((c2[3] - m2) * r2 * cgv.w + cbv.w);
  *(uint2*)(cxb + (size_t)row * 1024 + i) = pk.p;
}

// ---------- fused support path, MFMA version ----------
// Identities (LN is affine; raw v suffices):
//   logits[m,h] = SCALE*( rstd_m*(dotv[m,h] - mean_m*B_h) + A_h ),  dotv = v @ (g*u_h)
//   r[h,c]      = g_c*( sum_m wt[h,m]*v[m,c] - mu_h ) + b_c,  wt = attn*rstd, mu_h = sum attn*rstd*mean
__global__ __launch_bounds__(256) void suppattn_k(
    const float* __restrict__ support, const float* __restrict__ lgw, const float* __restrict__ lbw,
    const ushort_t* __restrict__ U, ushort_t* __restrict__ R)
{
  __shared__ ushort_t S[64 * 512];       // raw v bf16, chunk-swizzled rows (1KB each)
  __shared__ ushort_t UG[9 * 512];       // (g*u_h) bf16, row 8 = zeros, swizzled
  __shared__ float WT[8][64];
  __shared__ __align__(16) float MEANR[64];
  __shared__ __align__(16) float RSTDR[64];
  __shared__ float PMAX[4][8], PSUM[4][8], PMU[4][8];
  __shared__ float AB[2][8];
  __shared__ float MUH[8];

  int bb = blockIdx.x, tid = threadIdx.x, w = tid >> 6, l = tid & 63;
  const ushort_t* Ub = U + (size_t)bb * 4096;

  // --- UG build: UG[h][c] = g[c]*u[h][c]; row 8 zeros ---
  for (int id = tid; id < 576; id += 256){
    int hr = id >> 6, cc = id & 63;
    int byteoff = hr * 1024 + (((cc & 56) | ((cc & 7) ^ (hr & 7))) << 4);
    uint4* dst = (uint4*)((char*)UG + byteoff);
    if (hr < 8){
      s16x8 uv = *(const s16x8*)(Ub + hr * 512 + cc * 8);
      float4 g0 = *(const float4*)(lgw + cc * 8);
      float4 g1 = *(const float4*)(lgw + cc * 8 + 4);
      float ga[8] = { g0.x, g0.y, g0.z, g0.w, g1.x, g1.y, g1.z, g1.w };
      union { ushort_t u[8]; uint4 p; } pk;
      #pragma unroll
      for (int e = 0; e < 8; ++e) pk.u[e] = f2bf(ga[e] * bf2f((ushort_t)uv[e]));
      *dst = pk.p;
    } else {
      *dst = make_uint4(0u, 0u, 0u, 0u);
    }
  }

  // --- A/B pass: wave w handles heads 2w, 2w+1 ---
  {
    int h0 = 2 * w, h1 = 2 * w + 1;
    s16x8 u0 = *(const s16x8*)(Ub + h0 * 512 + l * 8);
    s16x8 u1 = *(const s16x8*)(Ub + h1 * 512 + l * 8);
    float4 g0 = *(const float4*)(lgw + l * 8), g1 = *(const float4*)(lgw + l * 8 + 4);
    float4 c0 = *(const float4*)(lbw + l * 8), c1 = *(const float4*)(lbw + l * 8 + 4);
    float ga[8] = { g0.x, g0.y, g0.z, g0.w, g1.x, g1.y, g1.z, g1.w };
    float ba[8] = { c0.x, c0.y, c0.z, c0.w, c1.x, c1.y, c1.z, c1.w };
    float A0 = 0.f, B0 = 0.f, A1 = 0.f, B1 = 0.f;
    #pragma unroll
    for (int e = 0; e < 8; ++e){
      float x0 = bf2f((ushort_t)u0[e]), x1 = bf2f((ushort_t)u1[e]);
      A0 += ba[e] * x0; B0 += ga[e] * x0;
      A1 += ba[e] * x1; B1 += ga[e] * x1;
    }
    A0 = wave_sum(A0); B0 = wave_sum(B0); A1 = wave_sum(A1); B1 = wave_sum(B1);
    if (l == 0){ AB[0][h0] = A0; AB[1][h0] = B0; AB[0][h1] = A1; AB[1][h1] = B1; }
  }

  // --- load raw v (row per wave, coalesced 2KB), stats, store S bf16 swizzled ---
  for (int i = 0; i < 16; ++i){
    int m = i * 4 + w;
    const float* row = support + ((size_t)bb * 64 + m) * 512 + l * 8;
    float4 a0 = *(const float4*)row, a1 = *(const float4*)(row + 4);
    float v[8] = { a0.x, a0.y, a0.z, a0.w, a1.x, a1.y, a1.z, a1.w };
    float s = 0.f, q = 0.f;
    union { ushort_t u[8]; uint4 p; } pk;
    #pragma unroll
    for (int e = 0; e < 8; ++e){ s += v[e]; q += v[e] * v[e]; pk.u[e] = f2bf(v[e]); }
    int byteoff = m * 1024 + (((l & 56) | ((l & 7) ^ (m & 7))) << 4);
    *(uint4*)((char*)S + byteoff) = pk.p;
    s = wave_sum(s); q = wave_sum(q);
    if (l == 0){
      float mean = s * (1.0f / 512.0f);
      float var = q * (1.0f / 512.0f) - mean * mean;
      MEANR[m] = mean; RSTDR[m] = rsqrtf(var + 1e-5f);
    }
  }
  __syncthreads();

  // --- dotv via MFMA: wave w owns m-tile w (rows w*16..w*16+15) ---
  int l15 = l & 15, lk = l >> 4;
  int hr = (l15 < 8) ? l15 : 8;
  int arowb = (w * 16 + l15) * 1024;
  int hrowb = hr * 1024;
  f32x4 dacc = (f32x4){0.f, 0.f, 0.f, 0.f};
  #pragma unroll
  for (int ks = 0; ks < 16; ++ks){
    int cc = ks * 4 + lk;
    s16x8 afr = *(const s16x8*)((char*)S + arowb + (((cc & 56) | ((cc & 7) ^ (l15 & 7))) << 4));
    s16x8 bfr = *(const s16x8*)((char*)UG + hrowb + (((cc & 56) | ((cc & 7) ^ (hr & 7))) << 4));
    dacc = __builtin_amdgcn_mfma_f32_16x16x32_bf16(afr, bfr, dacc, 0, 0, 0);
  }

  // --- logits transform + distributed softmax (col h = l15, rows r0..r0+3) ---
  int r0 = w * 16 + lk * 4;
  float4 mns = *(const float4*)(MEANR + r0);
  float4 rst = *(const float4*)(RSTDR + r0);
  float mn[4] = { mns.x, mns.y, mns.z, mns.w };
  float rs[4] = { rst.x, rst.y, rst.z, rst.w };
  float Ah = AB[0][l15 & 7], Bh = AB[1][l15 & 7];
  float lg[4];
  #pragma unroll
  for (int j = 0; j < 4; ++j)
    lg[j] = 0.08838834764831845f * (rs[j] * (dacc[j] - mn[j] * Bh) + Ah);
  float lmax = fmaxf(fmaxf(lg[0], lg[1]), fmaxf(lg[2], lg[3]));
  lmax = fmaxf(lmax, __shfl_xor(lmax, 16));
  lmax = fmaxf(lmax, __shfl_xor(lmax, 32));
  if (l < 8) PMAX[w][l] = lmax;
  __syncthreads();
  float gmax = fmaxf(fmaxf(PMAX[0][l15 & 7], PMAX[1][l15 & 7]),
                     fmaxf(PMAX[2][l15 & 7], PMAX[3][l15 & 7]));
  float e4[4]; float ls = 0.f, lm = 0.f;
  #pragma unroll
  for (int j = 0; j < 4; ++j){
    e4[j] = __expf(lg[j] - gmax);
    ls += e4[j];
    lm += e4[j] * rs[j] * mn[j];
  }
  ls += __shfl_xor(ls, 16); ls += __shfl_xor(ls, 32);
  lm += __shfl_xor(lm, 16); lm += __shfl_xor(lm, 32);
  if (l < 8){ PSUM[w][l] = ls; PMU[w][l] = lm; }
  __syncthreads();
  float Sh = PSUM[0][l15 & 7] + PSUM[1][l15 & 7] + PSUM[2][l15 & 7] + PSUM[3][l15 & 7];
  float inv = 1.0f / Sh;
  if (l15 < 8){
    #pragma unroll
    for (int j = 0; j < 4; ++j) WT[l15][r0 + j] = e4[j] * rs[j] * inv;
  }
  if (w == 0 && l < 8){
    MUH[l] = (PMU[0][l] + PMU[1][l] + PMU[2][l] + PMU[3][l]) * inv;
  }
  __syncthreads();

  // --- phase2: wave w handles heads 2w, 2w+1; lane owns c-chunk l (8 elems) ---
  int h0 = 2 * w, h1 = 2 * w + 1;
  float acc0[8] = {0.f,0.f,0.f,0.f,0.f,0.f,0.f,0.f};
  float acc1[8] = {0.f,0.f,0.f,0.f,0.f,0.f,0.f,0.f};
  #pragma unroll 4
  for (int m = 0; m < 64; ++m){
    s16x8 sv = *(const s16x8*)((char*)S + m * 1024 + (((l & 56) | ((l & 7) ^ (m & 7))) << 4));
    float f0 = WT[h0][m], f1 = WT[h1][m];
    #pragma unroll
    for (int e = 0; e < 8; ++e){
      float x = bf2f((ushort_t)sv[e]);
      acc0[e] += f0 * x;
      acc1[e] += f1 * x;
    }
  }
  {
    float4 g0 = *(const float4*)(lgw + l * 8), g1 = *(const float4*)(lgw + l * 8 + 4);
    float4 c0 = *(const float4*)(lbw + l * 8), c1 = *(const float4*)(lbw + l * 8 + 4);
    float ga[8] = { g0.x, g0.y, g0.z, g0.w, g1.x, g1.y, g1.z, g1.w };
    float ba[8] = { c0.x, c0.y, c0.z, c0.w, c1.x, c1.y, c1.z, c1.w };
    float mu0 = MUH[h0], mu1 = MUH[h1];
    union { ushort_t u[8]; uint4 p; } p0, p1;
    #pragma unroll
    for (int e = 0; e < 8; ++e){
      p0.u[e] = f2bf(ga[e] * (acc0[e] - mu0) + ba[e]);
      p1.u[e] = f2bf(ga[e] * (acc1[e] - mu1) + ba[e]);
    }
    *(uint4*)(R + (size_t)bb * 4096 + h0 * 512 + l * 8) = p0.p;
    *(uint4*)(R + (size_t)bb * 4096 + h1 * 512 + l * 8) = p1.p;
  }
}

// ---------- bf16 MFMA GEMM: C = [gelu](A @ Bt^T + bias) [+ R]; Bt is [N][K] ----------
#define GLL16(gsrc, ldst) \
  __builtin_amdgcn_global_load_lds((const __attribute__((address_space(1))) unsigned int*)(gsrc), \
                                   (__attribute__((address_space(3))) unsigned int*)(ldst), 16, 0, 0)

template<bool GELU, bool BIAS, bool WF32, bool WBF16, bool RESID>
__global__ __launch_bounds__(256, 2) void gemm_k(
    const ushort_t* __restrict__ A, int lda, long long aZ,
    const ushort_t* __restrict__ Bt, int ldb, long long bZ,
    const float* __restrict__ bias, long long biasZ,
    float* __restrict__ C, int ldc, long long cZ,
    ushort_t* __restrict__ Cb, int ldcb, long long cbZ,
    const float* __restrict__ R, int ldr,
    int M, int N, int K)
{
  __shared__ ushort_t smem[4][128 * 64];
  int tid = threadIdx.x, lane = tid & 63, w = tid >> 6;
  int z = blockIdx.z;
  A  += (size_t)aZ * z;
  Bt += (size_t)bZ * z;
  if (BIAS)  bias += (size_t)biasZ * z;
  if (WF32)  C    += (size_t)cZ * z;
  if (WBF16) Cb   += (size_t)cbZ * z;
  int m0 = blockIdx.y * 128, n0 = blockIdx.x * 128;
  int nk = K >> 6;

  auto stage = [&](int buf, int kt){
    int k0 = kt << 6;
    #pragma unroll
    for (int i = 0; i < 4; ++i){
      int c = ((w << 2) + i) * 64 + lane;
      int rowl = c >> 3, sp = c & 7;
      int sg = sp ^ (rowl & 7);
      const ushort_t* srcA = A + (size_t)(m0 + rowl) * lda + (k0 + sg * 8);
      GLL16(srcA, &smem[buf][((w << 2) + i) * 512]);
    }
    #pragma unroll
    for (int i = 0; i < 4; ++i){
      int c = ((w << 2) + i) * 64 + lane;
      int rowl = c >> 3, sp = c & 7;
      int sg = sp ^ (rowl & 7);
      const ushort_t* srcB = Bt + (size_t)(n0 + rowl) * ldb + (k0 + sg * 8);
      GLL16(srcB, &smem[2 + buf][((w << 2) + i) * 512]);
    }
  };

  int qrow = w >> 1, qcol = w & 1;
  int l15 = lane & 15, lk = lane >> 4, l7 = lane & 7;
  int sb0 = ((0 + lk) ^ l7) << 4;
  int sb1 = ((4 + lk) ^ l7) << 4;
  int arow = (qrow * 64 + l15) * 128;
  int brow = (qcol * 64 + l15) * 128;

  f32x4 acc[4][4];
  #pragma unroll
  for (int m = 0; m < 4; ++m)
    #pragma unroll
    for (int n = 0; n < 4; ++n)
      acc[m][n] = (f32x4){0.f, 0.f, 0.f, 0.f};

  stage(0, 0);
  asm volatile("s_waitcnt vmcnt(0)" ::: "memory");
  __syncthreads();
  for (int kt = 0; kt < nk; ++kt){
    int cur = kt & 1;
    if (kt + 1 < nk) stage((kt + 1) & 1, kt + 1);
    const char* ab = (const char*)&smem[cur][0];
    const char* bb = (const char*)&smem[2 + cur][0];
    s16x8 af[4][2], bfv[4][2];
    #pragma unroll
    for (int m = 0; m < 4; ++m){
      af[m][0] = *(const s16x8*)(ab + arow + m * 2048 + sb0);
      af[m][1] = *(const s16x8*)(ab + arow + m * 2048 + sb1);
    }
    #pragma unroll
    for (int n = 0; n < 4; ++n){
      bfv[n][0] = *(const s16x8*)(bb + brow + n * 2048 + sb0);
      bfv[n][1] = *(const s16x8*)(bb + brow + n * 2048 + sb1);
    }
    #pragma unroll
    for (int kb = 0; kb < 2; ++kb)
      #pragma unroll
      for (int m = 0; m < 4; ++m)
        #pragma unroll
        for (int n = 0; n < 4; ++n)
          acc[m][n] = __builtin_amdgcn_mfma_f32_16x16x32_bf16(af[m][kb], bfv[n][kb], acc[m][n], 0, 0, 0);
    asm volatile("s_waitcnt vmcnt(0)" ::: "memory");
    __syncthreads();
  }

  #pragma unroll
  for (int n = 0; n < 4; ++n){
    int col = n0 + qcol * 64 + n * 16 + l15;
    float bvv = BIAS ? bias[col] : 0.0f;
    #pragma unroll
    for (int m = 0; m < 4; ++m){
      int rbase = m0 + qrow * 64 + m * 16 + lk * 4;
      #pragma unroll
      for (int r = 0; r < 4; ++r){
        float x = acc[m][n][r] + bvv;
        if (GELU) x = gelu_f(x);
        int row = rbase + r;
        if (RESID) x += R[(size_t)row * ldr + col];
        if (WF32)  C[(size_t)row * ldc + col] = x;
        if (WBF16) Cb[(size_t)row * ldcb + col] = f2bf(x);
      }
    }
  }
}

// ---------- host ----------
extern "C" void kernel_launch(void* const* d_in, const int* in_sizes, int n_in,
                              void* d_out, int out_size, void* d_ws, size_t ws_size,
                              hipStream_t stream)
{
  (void)in_sizes; (void)n_in; (void)out_size;
  const float* states      = (const float*)d_in[0];
  const float* time_values = (const float*)d_in[1];
  const float* class_sum   = (const float*)d_in[2];
  const float* support     = (const float*)d_in[3];
  const float* trunk_ln_g  = (const float*)d_in[4];
  const float* trunk_ln_b  = (const float*)d_in[5];
  const float* trunk_w1    = (const float*)d_in[6];
  const float* trunk_b1    = (const float*)d_in[7];
  const float* trunk_w2    = (const float*)d_in[8];
  const float* trunk_b2    = (const float*)d_in[9];
  const float* mem_ln_g    = (const float*)d_in[10];
  const float* mem_ln_b    = (const float*)d_in[11];
  const float* mem_w       = (const float*)d_in[12];
  const float* mem_b       = (const float*)d_in[13];
  const float* wq          = (const float*)d_in[14];
  const float* bq          = (const float*)d_in[15];
  const float* wk          = (const float*)d_in[16];
  /* d_in[17] = bk: unused (softmax shift invariance) */
  const float* wv          = (const float*)d_in[18];
  const float* bvp         = (const float*)d_in[19];
  const float* wo          = (const float*)d_in[20];
  const float* bo          = (const float*)d_in[21];
  const float* pre_g       = (const float*)d_in[22];
  const float* pre_b       = (const float*)d_in[23];
  const float* film_w      = (const float*)d_in[24];
  const float* film_b      = (const float*)d_in[25];
  const float* cond_g      = (const float*)d_in[26];
  const float* cond_b      = (const float*)d_in[27];
  const float* cond_w1     = (const float*)d_in[28];
  const float* cond_b1     = (const float*)d_in[29];
  const float* cond_w2     = (const float*)d_in[30];
  const float* cond_b2     = (const float*)d_in[31];
  const float* head_g      = (const float*)d_in[32];
  const float* head_bb     = (const float*)d_in[33];
  const float* head_w1     = (const float*)d_in[34];
  const float* head_b1     = (const float*)d_in[35];
  const float* head_w2     = (const float*)d_in[36];
  const float* head_b2     = (const float*)d_in[37];
  float* out = (float*)d_out;

  char* ws = (char*)d_ws;
  size_t off = 0;
  auto alloc = [&](size_t bytes)->char*{
    char* p = ws + off;
    off += (bytes + 255) & ~(size_t)255;
    return p;
  };
  ushort_t* tw1T   = (ushort_t*)alloc((size_t)640 * 1024 * 2);
  ushort_t* tw2T   = (ushort_t*)alloc((size_t)1024 * 1024 * 2);
  ushort_t* wqT    = (ushort_t*)alloc((size_t)1024 * 1024 * 2);
  ushort_t* wkT    = (ushort_t*)alloc((size_t)1024 * 1024 * 2);
  ushort_t* wvT    = (ushort_t*)alloc((size_t)1024 * 1024 * 2);
  ushort_t* woT    = (ushort_t*)alloc((size_t)1024 * 1024 * 2);
  ushort_t* memw_b = (ushort_t*)alloc((size_t)512 * 1024 * 2);
  ushort_t* filmWT = (ushort_t*)alloc((size_t)512 * 2048 * 2);
  ushort_t* cw1T   = (ushort_t*)alloc((size_t)1024 * 1024 * 2);
  ushort_t* cw2T   = (ushort_t*)alloc((size_t)1024 * 1024 * 2);
  ushort_t* hw1T   = (ushort_t*)alloc((size_t)1024 * 1024 * 2);
  ushort_t* hw2T   = (ushort_t*)alloc((size_t)1024 * 512 * 2);
  ushort_t* K2     = (ushort_t*)alloc((size_t)512 * 1024 * 2);
  ushort_t* V2T    = (ushort_t*)alloc((size_t)1024 * 512 * 2);
  float*    bv2    = (float*)   alloc((size_t)1024 * 4);
  ushort_t* xnb    = (ushort_t*)alloc((size_t)4096 * 640 * 2);
  ushort_t* h1     = (ushort_t*)alloc((size_t)4096 * 1024 * 2);
  float*    gf     = (float*)   alloc((size_t)4096 * 1024 * 4);
  ushort_t* gb     = (ushort_t*)alloc((size_t)4096 * 1024 * 2);
  ushort_t* qb     = (ushort_t*)alloc((size_t)4096 * 1024 * 2);
  ushort_t* U      = (ushort_t*)alloc((size_t)4096 * 4096 * 2);
  ushort_t* Rb     = (ushort_t*)alloc((size_t)4096 * 4096 * 2);
  ushort_t* sumb   = (ushort_t*)alloc((size_t)4096 * 1024 * 2);
  float*    asf    = (float*)   alloc((size_t)4096 * 1024 * 4);
  ushort_t* csb    = (ushort_t*)alloc((size_t)4096 * 512 * 2);
  float*    filmf  = (float*)   alloc((size_t)4096 * 2048 * 4);
  float*    c2f    = (float*)   alloc((size_t)4096 * 1024 * 4);
  ushort_t* cxb    = (ushort_t*)alloc((size_t)4096 * 1024 * 2);
  ushort_t* c1     = (ushort_t*)alloc((size_t)4096 * 1024 * 2);
  float*    cond2f = (float*)   alloc((size_t)4096 * 1024 * 4);
  ushort_t* hxb    = (ushort_t*)alloc((size_t)4096 * 1024 * 2);
  ushort_t* h3     = (ushort_t*)alloc((size_t)4096 * 1024 * 2);
  if (off > ws_size) return;

  dim3 tb(32, 8);
  transpose_cast_k<<<dim3(32, 20), tb, 0, stream>>>(trunk_w1, tw1T, 640, 1024);
  transpose_cast_k<<<dim3(32, 32), tb, 0, stream>>>(trunk_w2, tw2T, 1024, 1024);
  transpose_cast_k<<<dim3(32, 32), tb, 0, stream>>>(wq, wqT, 1024, 1024);
  transpose_cast_k<<<dim3(32, 32), tb, 0, stream>>>(wk, wkT, 1024, 1024);
  transpose_cast_k<<<dim3(32, 32), tb, 0, stream>>>(wv, wvT, 1024, 1024);
  transpose_cast_k<<<dim3(32, 32), tb, 0, stream>>>(wo, woT, 1024, 1024);
  transpose_cast_k<<<dim3(64, 16), tb, 0, stream>>>(film_w, filmWT, 512, 2048);
  transpose_cast_k<<<dim3(32, 32), tb, 0, stream>>>(cond_w1, cw1T, 1024, 1024);
  transpose_cast_k<<<dim3(32, 32), tb, 0, stream>>>(cond_w2, cw2T, 1024, 1024);
  transpose_cast_k<<<dim3(32, 32), tb, 0, stream>>>(head_w1, hw1T, 1024, 1024);
  transpose_cast_k<<<dim3(16, 32), tb, 0, stream>>>(head_w2, hw2T, 1024, 512);
  cast4_k<<<512, 256, 0, stream>>>(mem_w, memw_b, 512 * 1024);
  cast4_k<<<2048, 256, 0, stream>>>(class_sum, csb, 4096 * 512);
  bv2_k<<<8, 128, 0, stream>>>(mem_b, wv, bvp, bv2);

  gemm_k<false, false, false, true, false><<<dim3(8, 4, 1), 256, 0, stream>>>(
      memw_b, 1024, 0, wkT, 1024, 0, nullptr, 0, nullptr, 0, 0, K2, 1024, 0, nullptr, 0, 512, 1024, 1024);
  gemm_k<false, false, false, true, false><<<dim3(4, 8, 1), 256, 0, stream>>>(
      wvT, 1024, 0, memw_b, 1024, 0, nullptr, 0, nullptr, 0, 0, V2T, 512, 0, nullptr, 0, 1024, 512, 1024);

  ln_trunk_k<<<4096, 256, 0, stream>>>(states, time_values, trunk_ln_g, trunk_ln_b, xnb);
  gemm_k<true, true, false, true, false><<<dim3(8, 32, 1), 256, 0, stream>>>(
      xnb, 640, 0, tw1T, 640, 0, trunk_b1, 0, nullptr, 0, 0, h1, 1024, 0, nullptr, 0, 4096, 1024, 640);
  gemm_k<false, true, true, true, false><<<dim3(8, 32, 1), 256, 0, stream>>>(
      h1, 1024, 0, tw2T, 1024, 0, trunk_b2, 0, gf, 1024, 0, gb, 1024, 0, nullptr, 0, 4096, 1024, 1024);
  gemm_k<false, true, false, true, false><<<dim3(8, 32, 1), 256, 0, stream>>>(
      gb, 1024, 0, wqT, 1024, 0, bq, 0, nullptr, 0, 0, qb, 1024, 0, nullptr, 0, 4096, 1024, 1024);
  gemm_k<false, false, false, true, false><<<dim3(4, 32, 8), 256, 0, stream>>>(
      qb, 1024, 128, K2, 1024, 128, nullptr, 0, nullptr, 0, 0, U, 4096, 512, nullptr, 0, 4096, 512, 128);

  suppattn_k<<<4096, 256, 0, stream>>>(support, mem_ln_g, mem_ln_b, U, Rb);

  gemm_k<false, true, false, true, false><<<dim3(1, 32, 8), 256, 0, stream>>>(
      Rb, 4096, 512, V2T, 512, 65536, bv2, 128, nullptr, 0, 0, sumb, 1024, 128, nullptr, 0, 4096, 128, 512);

  gemm_k<false, true, true, false, false><<<dim3(8, 32, 1), 256, 0, stream>>>(
      sumb, 1024, 0, woT, 1024, 0, bo, 0, asf, 1024, 0, nullptr, 0, 0, nullptr, 0, 4096, 1024, 1024);
  gemm_k<false, true, true, false, false><<<dim3(16, 32, 1), 256, 0, stream>>>(
      csb, 512, 0, filmWT, 512, 0, film_b, 0, filmf, 2048, 0, nullptr, 0, 0, nullptr, 0, 4096, 2048, 512);

  fuse_film_k<<<4096, 256, 0, stream>>>(gf, asf, filmf, pre_g, pre_b, cond_g, cond_b, c2f, cxb);

  gemm_k<true, true, false, true, false><<<dim3(8, 32, 1), 256, 0, stream>>>(
      cxb, 1024, 0, cw1T, 1024, 0, cond_b1, 0, nullptr, 0, 0, c1, 1024, 0, nullptr, 0, 4096, 1024, 1024);
  gemm_k<false, true, true, false, true><<<dim3(8, 32, 1), 256, 0, stream>>>(
      c1, 1024, 0, cw2T, 1024, 0, cond_b2, 0, cond2f, 1024, 0, nullptr, 0, 0, c2f, 1024, 4096, 1024, 1024);
  ln_rows_k<<<4096, 256, 0, stream>>>(cond2f, head_g, head_bb, hxb, 1024);
  gemm_k<true, true, false, true, false><<<dim3(8, 32, 1), 256, 0, stream>>>(
      hxb, 1024, 0, hw1T, 1024, 0, head_b1, 0, nullptr, 0, 0, h3, 1024, 0, nullptr, 0, 4096, 1024, 1024);
  gemm_k<false, true, true, false, false><<<dim3(4, 32, 1), 256, 0, stream>>>(
      h3, 1024, 0, hw2T, 1024, 0, head_b2, 0, out, 512, 0, nullptr, 0, 0, nullptr, 0, 4096, 512, 1024);
}

// Round 4
// 481.702 us; speedup vs baseline: 2.7747x; 1.1916x over previous
//
#include <hip/hip_runtime.h>
#include <cstdint>
#include <cstddef>

typedef unsigned short ushort_t;
typedef short s16x8 __attribute__((ext_vector_type(8)));
typedef float f32x4 __attribute__((ext_vector_type(4)));

// ---------- small helpers ----------
__device__ __forceinline__ float bf2f(ushort_t h){
  union { unsigned int u; float f; } v; v.u = ((unsigned int)h) << 16; return v.f;
}
__device__ __forceinline__ ushort_t f2bf(float x){
  union { float f; unsigned int u; } v; v.f = x;
  unsigned int r = v.u + 0x7FFFu + ((v.u >> 16) & 1u);
  return (ushort_t)(r >> 16);
}
__device__ __forceinline__ float gelu_f(float x){
  return 0.5f * x * (1.0f + erff(x * 0.7071067811865475f));
}
__device__ __forceinline__ float wave_sum(float v){
  #pragma unroll
  for (int o = 32; o; o >>= 1) v += __shfl_xor(v, o);
  return v;
}
__device__ __forceinline__ void block_reduce2(float& s, float& q, float* red){
  s = wave_sum(s); q = wave_sum(q);
  int w = threadIdx.x >> 6, lane = threadIdx.x & 63, nw = blockDim.x >> 6;
  if (lane == 0){ red[w] = s; red[8 + w] = q; }
  __syncthreads();
  float ts = 0.f, tq = 0.f;
  for (int i = 0; i < nw; ++i){ ts += red[i]; tq += red[8 + i]; }
  __syncthreads();
  s = ts; q = tq;
}

// ---------- fused weight prep: 11 transposes + 2 casts + bv2, one launch ----------
struct TDesc { const float* in; ushort_t* out; int K; int N; int start; };
struct PrepArgs {
  TDesc t[11];
  int ntiles_end;
  int cast1_blocks;
  int cast_end;
  const float* memw; ushort_t* memwb;
  const float* csum; ushort_t* csb;
  const float* memb; const float* wv; const float* bvp; float* bv2;
};

__global__ __launch_bounds__(256) void prep_k(PrepArgs a){
  int bid = blockIdx.x, tid = threadIdx.x;
  if (bid < a.ntiles_end){
    int d = 0;
    #pragma unroll
    for (int i = 1; i < 11; ++i) if (bid >= a.t[i].start) d = i;
    TDesc td = a.t[d];
    int tile = bid - td.start;
    int tilesx = td.N >> 5;
    int n0 = (tile % tilesx) << 5, k0 = (tile / tilesx) << 5;
    __shared__ float tbuf[32][33];
    int tx = tid & 31, ty = tid >> 5;
    #pragma unroll
    for (int j = 0; j < 32; j += 8)
      tbuf[ty + j][tx] = td.in[(size_t)(k0 + ty + j) * td.N + (n0 + tx)];
    __syncthreads();
    #pragma unroll
    for (int j = 0; j < 32; j += 8)
      td.out[(size_t)(n0 + ty + j) * td.K + (k0 + tx)] = f2bf(tbuf[tx][ty + j]);
  } else if (bid < a.cast_end){
    int ci = bid - a.ntiles_end;
    const float* src; ushort_t* dst; int i;
    if (ci < a.cast1_blocks){ src = a.memw; dst = a.memwb; i = ci * 1024 + tid * 4; }
    else { src = a.csum; dst = a.csb; i = (ci - a.cast1_blocks) * 1024 + tid * 4; }
    float4 v = *(const float4*)(src + i);
    union { ushort_t u[4]; uint2 p; } pk;
    pk.u[0] = f2bf(v.x); pk.u[1] = f2bf(v.y); pk.u[2] = f2bf(v.z); pk.u[3] = f2bf(v.w);
    *(uint2*)(dst + i) = pk.p;
  } else {
    int col = (bid - a.cast_end) * 256 + tid;
    float a0 = 0.f, a1 = 0.f, a2 = 0.f, a3 = 0.f;
    for (int j = 0; j < 1024; j += 4){
      a0 += a.memb[j + 0] * a.wv[(size_t)(j + 0) * 1024 + col];
      a1 += a.memb[j + 1] * a.wv[(size_t)(j + 1) * 1024 + col];
      a2 += a.memb[j + 2] * a.wv[(size_t)(j + 2) * 1024 + col];
      a3 += a.memb[j + 3] * a.wv[(size_t)(j + 3) * 1024 + col];
    }
    a.bv2[col] = a0 + a1 + a2 + a3 + a.bvp[col];
  }
}

// ---------- LN kernels ----------
__global__ __launch_bounds__(256) void ln_trunk_k(const float* __restrict__ states, const float* __restrict__ tv,
    const float* __restrict__ g, const float* __restrict__ b, ushort_t* __restrict__ out){
  int row = blockIdx.x, tid = threadIdx.x;
  __shared__ float buf[640];
  __shared__ float red[16];
  float t = tv[row];
  for (int i = tid; i < 640; i += 256){
    float v;
    if (i < 512) v = states[(size_t)row * 512 + i];
    else {
      int j = i - 512, jj = j & 63;
      float fr = expf(6.907755278982137f * ((float)jj * (1.0f / 63.0f)));
      float ang = 6.283185307179586f * t * fr;
      v = (j < 64) ? sinf(ang) : cosf(ang);
    }
    buf[i] = v;
  }
  __syncthreads();
  float s = 0.f, q = 0.f;
  for (int i = tid; i < 640; i += 256){ float v = buf[i]; s += v; q += v * v; }
  block_reduce2(s, q, red);
  float mean = s * (1.0f / 640.0f);
  float var = q * (1.0f / 640.0f) - mean * mean;
  float rstd = rsqrtf(var + 1e-5f);
  for (int i = tid; i < 640; i += 256)
    out[(size_t)row * 640 + i] = f2bf((buf[i] - mean) * rstd * g[i] + b[i]);
}

__global__ __launch_bounds__(256) void ln_rows_k(const float* __restrict__ in, const float* __restrict__ g,
    const float* __restrict__ b, ushort_t* __restrict__ out, int D){
  int row = blockIdx.x, tid = threadIdx.x, i = tid * 4;
  __shared__ float red[16];
  const float* x = in + (size_t)row * D;
  float4 v = *(const float4*)(x + i);
  float s = v.x + v.y + v.z + v.w;
  float q = v.x * v.x + v.y * v.y + v.z * v.z + v.w * v.w;
  block_reduce2(s, q, red);
  float invD = 1.0f / (float)D;
  float mean = s * invD, var = q * invD - mean * mean, rstd = rsqrtf(var + 1e-5f);
  union { ushort_t u[4]; uint2 p; } pk;
  pk.u[0] = f2bf((v.x - mean) * rstd * g[i + 0] + b[i + 0]);
  pk.u[1] = f2bf((v.y - mean) * rstd * g[i + 1] + b[i + 1]);
  pk.u[2] = f2bf((v.z - mean) * rstd * g[i + 2] + b[i + 2]);
  pk.u[3] = f2bf((v.w - mean) * rstd * g[i + 3] + b[i + 3]);
  *(uint2*)(out + (size_t)row * D + i) = pk.p;
}

__global__ __launch_bounds__(256) void fuse_film_k(const float* __restrict__ gf, const float* __restrict__ asf,
    const float* __restrict__ film, const float* __restrict__ pg, const float* __restrict__ pb,
    const float* __restrict__ cg, const float* __restrict__ cb,
    float* __restrict__ c2f, ushort_t* __restrict__ cxb){
  int row = blockIdx.x, tid = threadIdx.x, i = tid * 4;
  __shared__ float red[16];
  float4 a = *(const float4*)(gf + (size_t)row * 1024 + i);
  float4 d = *(const float4*)(asf + (size_t)row * 1024 + i);
  float x[4] = { a.x + d.x, a.y + d.y, a.z + d.z, a.w + d.w };
  float s = x[0] + x[1] + x[2] + x[3];
  float q = x[0]*x[0] + x[1]*x[1] + x[2]*x[2] + x[3]*x[3];
  block_reduce2(s, q, red);
  float mean = s * (1.0f / 1024.0f), var = q * (1.0f / 1024.0f) - mean * mean;
  float rstd = rsqrtf(var + 1e-5f);
  float4 pgv = *(const float4*)(pg + i), pbv = *(const float4*)(pb + i);
  float4 sc = *(const float4*)(film + (size_t)row * 2048 + i);
  float4 sh = *(const float4*)(film + (size_t)row * 2048 + 1024 + i);
  float c2[4];
  {
    float pgx[4] = { pgv.x, pgv.y, pgv.z, pgv.w };
    float pbx[4] = { pbv.x, pbv.y, pbv.z, pbv.w };
    float scx[4] = { sc.x, sc.y, sc.z, sc.w };
    float shx[4] = { sh.x, sh.y, sh.z, sh.w };
    #pragma unroll
    for (int e = 0; e < 4; ++e){
      float cc = (x[e] - mean) * rstd * pgx[e] + pbx[e];
      c2[e] = (1.0f + scx[e]) * cc + shx[e];
    }
  }
  *(float4*)(c2f + (size_t)row * 1024 + i) = make_float4(c2[0], c2[1], c2[2], c2[3]);
  float s2 = c2[0] + c2[1] + c2[2] + c2[3];
  float q2 = c2[0]*c2[0] + c2[1]*c2[1] + c2[2]*c2[2] + c2[3]*c2[3];
  block_reduce2(s2, q2, red);
  float m2 = s2 * (1.0f / 1024.0f), v2 = q2 * (1.0f / 1024.0f) - m2 * m2;
  float r2 = rsqrtf(v2 + 1e-5f);
  float4 cgv = *(const float4*)(cg + i), cbv = *(const float4*)(cb + i);
  union { ushort_t u[4]; uint2 p; } pk;
  pk.u[0] = f2bf((c2[0] - m2) * r2 * cgv.x + cbv.x);
  pk.u[1] = f2bf((c2[1] - m2) * r2 * cgv.y + cbv.y);
  pk.u[2] = f2bf((c2[2] - m2) * r2 * cgv.z + cbv.z);
  pk.u[3] = f2bf((c2[3] - m2) * r2 * cgv.w + cbv.w);
  *(uint2*)(cxb + (size_t)row * 1024 + i) = pk.p;
}

// ---------- fused support path, MFMA version (stats via MFMA too) ----------
// logits[m,h] = SCALE*( rstd_m*(dotv[m,h] - mean_m*B_h) + A_h ),  dotv = v @ (g*u_h)
// rowsum_m    = dotv[m, col8] with UG row8 = ones
// sumsq_m     = diag(V V^T) via mfma(afr, afr, sacc)
// r[h,c]      = g_c*( sum_m wt[h,m]*v[m,c] - mu_h ) + b_c,  wt = attn*rstd
__global__ __launch_bounds__(256, 2) void suppattn_k(
    const float* __restrict__ support, const float* __restrict__ lgw, const float* __restrict__ lbw,
    const ushort_t* __restrict__ U, ushort_t* __restrict__ R)
{
  __shared__ ushort_t S[64 * 512];       // raw v bf16, chunk-swizzled rows
  __shared__ ushort_t UG[9 * 512];       // (g*u_h) bf16; row 8 = ones
  __shared__ float WT[8][64];
  __shared__ float SUMV[64], SUMSQ[64];
  __shared__ __align__(16) float MEANR[64];
  __shared__ __align__(16) float RSTDR[64];
  __shared__ float PMAX[4][8], PSUM[4][8], PMU[4][8];
  __shared__ float AB[2][8];
  __shared__ float MUH[8];

  int bb = blockIdx.x, tid = threadIdx.x, w = tid >> 6, l = tid & 63;
  const ushort_t* Ub = U + (size_t)bb * 4096;

  // --- UG build: UG[h][c] = g[c]*u[h][c]; row 8 = bf16(1.0) ---
  for (int id = tid; id < 576; id += 256){
    int hr = id >> 6, cc = id & 63;
    int byteoff = hr * 1024 + (((cc & 56) | ((cc & 7) ^ (hr & 7))) << 4);
    uint4* dst = (uint4*)((char*)UG + byteoff);
    if (hr < 8){
      s16x8 uv = *(const s16x8*)(Ub + hr * 512 + cc * 8);
      float4 g0 = *(const float4*)(lgw + cc * 8);
      float4 g1 = *(const float4*)(lgw + cc * 8 + 4);
      float ga[8] = { g0.x, g0.y, g0.z, g0.w, g1.x, g1.y, g1.z, g1.w };
      union { ushort_t u[8]; uint4 p; } pk;
      #pragma unroll
      for (int e = 0; e < 8; ++e) pk.u[e] = f2bf(ga[e] * bf2f((ushort_t)uv[e]));
      *dst = pk.p;
    } else {
      *dst = make_uint4(0x3F803F80u, 0x3F803F80u, 0x3F803F80u, 0x3F803F80u);
    }
  }

  // --- A/B pass: wave w handles heads 2w, 2w+1 ---
  {
    int h0 = 2 * w, h1 = 2 * w + 1;
    s16x8 u0 = *(const s16x8*)(Ub + h0 * 512 + l * 8);
    s16x8 u1 = *(const s16x8*)(Ub + h1 * 512 + l * 8);
    float4 g0 = *(const float4*)(lgw + l * 8), g1 = *(const float4*)(lgw + l * 8 + 4);
    float4 c0 = *(const float4*)(lbw + l * 8), c1 = *(const float4*)(lbw + l * 8 + 4);
    float ga[8] = { g0.x, g0.y, g0.z, g0.w, g1.x, g1.y, g1.z, g1.w };
    float ba[8] = { c0.x, c0.y, c0.z, c0.w, c1.x, c1.y, c1.z, c1.w };
    float A0 = 0.f, B0 = 0.f, A1 = 0.f, B1 = 0.f;
    #pragma unroll
    for (int e = 0; e < 8; ++e){
      float x0 = bf2f((ushort_t)u0[e]), x1 = bf2f((ushort_t)u1[e]);
      A0 += ba[e] * x0; B0 += ga[e] * x0;
      A1 += ba[e] * x1; B1 += ga[e] * x1;
    }
    A0 = wave_sum(A0); B0 = wave_sum(B0); A1 = wave_sum(A1); B1 = wave_sum(B1);
    if (l == 0){ AB[0][h0] = A0; AB[1][h0] = B0; AB[0][h1] = A1; AB[1][h1] = B1; }
  }

  // --- streamed load+pack+store (no reductions; loads pipeline) ---
  #pragma unroll 4
  for (int i = 0; i < 16; ++i){
    int m = i * 4 + w;
    const float* row = support + ((size_t)bb * 64 + m) * 512 + l * 8;
    float4 a0 = *(const float4*)row, a1 = *(const float4*)(row + 4);
    union { ushort_t u[8]; uint4 p; } pk;
    pk.u[0] = f2bf(a0.x); pk.u[1] = f2bf(a0.y); pk.u[2] = f2bf(a0.z); pk.u[3] = f2bf(a0.w);
    pk.u[4] = f2bf(a1.x); pk.u[5] = f2bf(a1.y); pk.u[6] = f2bf(a1.z); pk.u[7] = f2bf(a1.w);
    int byteoff = m * 1024 + (((l & 56) | ((l & 7) ^ (m & 7))) << 4);
    *(uint4*)((char*)S + byteoff) = pk.p;
  }
  __syncthreads();

  // --- MFMA: dotv (+rowsum via ones-col) and V.V^T (diag = sumsq) ---
  int l15 = l & 15, lk = l >> 4;
  int hr = (l15 < 8) ? l15 : 8;
  int arowb = (w * 16 + l15) * 1024;
  int hrowb = hr * 1024;
  f32x4 dacc = (f32x4){0.f, 0.f, 0.f, 0.f};
  f32x4 sacc = (f32x4){0.f, 0.f, 0.f, 0.f};
  #pragma unroll
  for (int ks = 0; ks < 16; ++ks){
    int cc = ks * 4 + lk;
    s16x8 afr = *(const s16x8*)((char*)S + arowb + (((cc & 56) | ((cc & 7) ^ (l15 & 7))) << 4));
    s16x8 bfr = *(const s16x8*)((char*)UG + hrowb + (((cc & 56) | ((cc & 7) ^ (hr & 7))) << 4));
    dacc = __builtin_amdgcn_mfma_f32_16x16x32_bf16(afr, bfr, dacc, 0, 0, 0);
    sacc = __builtin_amdgcn_mfma_f32_16x16x32_bf16(afr, afr, sacc, 0, 0, 0);
  }
  if (l15 == 8){
    #pragma unroll
    for (int j = 0; j < 4; ++j) SUMV[w * 16 + lk * 4 + j] = dacc[j];
  }
  if ((l15 >> 2) == lk) SUMSQ[w * 16 + l15] = sacc[l15 & 3];
  __syncthreads();
  if (tid < 64){
    float mean = SUMV[tid] * (1.0f / 512.0f);
    float var = SUMSQ[tid] * (1.0f / 512.0f) - mean * mean;
    MEANR[tid] = mean;
    RSTDR[tid] = rsqrtf(var + 1e-5f);
  }
  __syncthreads();

  // --- logits transform + distributed softmax (col h = l15, rows r0..r0+3) ---
  int r0 = w * 16 + lk * 4;
  float4 mns = *(const float4*)(MEANR + r0);
  float4 rst = *(const float4*)(RSTDR + r0);
  float mn[4] = { mns.x, mns.y, mns.z, mns.w };
  float rs[4] = { rst.x, rst.y, rst.z, rst.w };
  float Ah = AB[0][l15 & 7], Bh = AB[1][l15 & 7];
  float lg[4];
  #pragma unroll
  for (int j = 0; j < 4; ++j)
    lg[j] = 0.08838834764831845f * (rs[j] * (dacc[j] - mn[j] * Bh) + Ah);
  float lmax = fmaxf(fmaxf(lg[0], lg[1]), fmaxf(lg[2], lg[3]));
  lmax = fmaxf(lmax, __shfl_xor(lmax, 16));
  lmax = fmaxf(lmax, __shfl_xor(lmax, 32));
  if (l < 8) PMAX[w][l] = lmax;
  __syncthreads();
  float gmax = fmaxf(fmaxf(PMAX[0][l15 & 7], PMAX[1][l15 & 7]),
                     fmaxf(PMAX[2][l15 & 7], PMAX[3][l15 & 7]));
  float e4[4]; float ls = 0.f, lm = 0.f;
  #pragma unroll
  for (int j = 0; j < 4; ++j){
    e4[j] = __expf(lg[j] - gmax);
    ls += e4[j];
    lm += e4[j] * rs[j] * mn[j];
  }
  ls += __shfl_xor(ls, 16); ls += __shfl_xor(ls, 32);
  lm += __shfl_xor(lm, 16); lm += __shfl_xor(lm, 32);
  if (l < 8){ PSUM[w][l] = ls; PMU[w][l] = lm; }
  __syncthreads();
  float Sh = PSUM[0][l15 & 7] + PSUM[1][l15 & 7] + PSUM[2][l15 & 7] + PSUM[3][l15 & 7];
  float inv = 1.0f / Sh;
  if (l15 < 8){
    #pragma unroll
    for (int j = 0; j < 4; ++j) WT[l15][r0 + j] = e4[j] * rs[j] * inv;
  }
  if (w == 0 && l < 8){
    MUH[l] = (PMU[0][l] + PMU[1][l] + PMU[2][l] + PMU[3][l]) * inv;
  }
  __syncthreads();

  // --- phase2: wave w handles heads 2w, 2w+1; lane owns c-chunk l (8 elems) ---
  int h0 = 2 * w, h1 = 2 * w + 1;
  float acc0[8] = {0.f,0.f,0.f,0.f,0.f,0.f,0.f,0.f};
  float acc1[8] = {0.f,0.f,0.f,0.f,0.f,0.f,0.f,0.f};
  #pragma unroll 4
  for (int m = 0; m < 64; ++m){
    s16x8 sv = *(const s16x8*)((char*)S + m * 1024 + (((l & 56) | ((l & 7) ^ (m & 7))) << 4));
    float f0 = WT[h0][m], f1 = WT[h1][m];
    #pragma unroll
    for (int e = 0; e < 8; ++e){
      float x = bf2f((ushort_t)sv[e]);
      acc0[e] += f0 * x;
      acc1[e] += f1 * x;
    }
  }
  {
    float4 g0 = *(const float4*)(lgw + l * 8), g1 = *(const float4*)(lgw + l * 8 + 4);
    float4 c0 = *(const float4*)(lbw + l * 8), c1 = *(const float4*)(lbw + l * 8 + 4);
    float ga[8] = { g0.x, g0.y, g0.z, g0.w, g1.x, g1.y, g1.z, g1.w };
    float ba[8] = { c0.x, c0.y, c0.z, c0.w, c1.x, c1.y, c1.z, c1.w };
    float mu0 = MUH[h0], mu1 = MUH[h1];
    union { ushort_t u[8]; uint4 p; } p0, p1;
    #pragma unroll
    for (int e = 0; e < 8; ++e){
      p0.u[e] = f2bf(ga[e] * (acc0[e] - mu0) + ba[e]);
      p1.u[e] = f2bf(ga[e] * (acc1[e] - mu1) + ba[e]);
    }
    *(uint4*)(R + (size_t)bb * 4096 + h0 * 512 + l * 8) = p0.p;
    *(uint4*)(R + (size_t)bb * 4096 + h1 * 512 + l * 8) = p1.p;
  }
}

// ---------- bf16 MFMA GEMM, BM=64 x BN=128 tile, 3 blocks/CU ----------
#define GLL16(gsrc, ldst) \
  __builtin_amdgcn_global_load_lds((const __attribute__((address_space(1))) unsigned int*)(gsrc), \
                                   (__attribute__((address_space(3))) unsigned int*)(ldst), 16, 0, 0)

template<bool GELU, bool BIAS, bool WF32, bool WBF16, bool RESID>
__global__ __launch_bounds__(256, 3) void gemm_k(
    const ushort_t* __restrict__ A, int lda, long long aZ,
    const ushort_t* __restrict__ Bt, int ldb, long long bZ,
    const float* __restrict__ bias, long long biasZ,
    float* __restrict__ C, int ldc, long long cZ,
    ushort_t* __restrict__ Cb, int ldcb, long long cbZ,
    const float* __restrict__ R, int ldr,
    int M, int N, int K)
{
  __shared__ ushort_t smA[2][64 * 64];    // 2 x 8KB
  __shared__ ushort_t smB[2][128 * 64];   // 2 x 16KB
  int tid = threadIdx.x, lane = tid & 63, w = tid >> 6;
  int z = blockIdx.z;
  A  += (size_t)aZ * z;
  Bt += (size_t)bZ * z;
  if (BIAS)  bias += (size_t)biasZ * z;
  if (WF32)  C    += (size_t)cZ * z;
  if (WBF16) Cb   += (size_t)cbZ * z;
  int m0 = blockIdx.y * 64, n0 = blockIdx.x * 128;
  int nk = K >> 6;

  auto stage = [&](int buf, int kt){
    int k0 = kt << 6;
    #pragma unroll
    for (int i = 0; i < 2; ++i){
      int c = ((w << 1) + i) * 64 + lane;
      int rowl = c >> 3, sp = c & 7;
      int sg = sp ^ (rowl & 7);
      GLL16(A + (size_t)(m0 + rowl) * lda + (k0 + sg * 8), &smA[buf][((w << 1) + i) * 512]);
    }
    #pragma unroll
    for (int i = 0; i < 4; ++i){
      int c = ((w << 2) + i) * 64 + lane;
      int rowl = c >> 3, sp = c & 7;
      int sg = sp ^ (rowl & 7);
      GLL16(Bt + (size_t)(n0 + rowl) * ldb + (k0 + sg * 8), &smB[buf][((w << 2) + i) * 512]);
    }
  };

  int qrow = w >> 1, qcol = w & 1;
  int l15 = lane & 15, lk = lane >> 4, l7 = lane & 7;
  int sb0 = ((0 + lk) ^ l7) << 4;
  int sb1 = ((4 + lk) ^ l7) << 4;
  int arow = (qrow * 32 + l15) * 128;
  int brow = (qcol * 64 + l15) * 128;

  f32x4 acc[2][4];
  #pragma unroll
  for (int m = 0; m < 2; ++m)
    #pragma unroll
    for (int n = 0; n < 4; ++n)
      acc[m][n] = (f32x4){0.f, 0.f, 0.f, 0.f};

  stage(0, 0);
  asm volatile("s_waitcnt vmcnt(0)" ::: "memory");
  __syncthreads();
  for (int kt = 0; kt < nk; ++kt){
    int cur = kt & 1;
    if (kt + 1 < nk) stage((kt + 1) & 1, kt + 1);
    const char* ab = (const char*)&smA[cur][0];
    const char* bbp = (const char*)&smB[cur][0];
    s16x8 af[2][2], bfv[4][2];
    #pragma unroll
    for (int m = 0; m < 2; ++m){
      af[m][0] = *(const s16x8*)(ab + arow + m * 2048 + sb0);
      af[m][1] = *(const s16x8*)(ab + arow + m * 2048 + sb1);
    }
    #pragma unroll
    for (int n = 0; n < 4; ++n){
      bfv[n][0] = *(const s16x8*)(bbp + brow + n * 2048 + sb0);
      bfv[n][1] = *(const s16x8*)(bbp + brow + n * 2048 + sb1);
    }
    #pragma unroll
    for (int kb = 0; kb < 2; ++kb)
      #pragma unroll
      for (int m = 0; m < 2; ++m)
        #pragma unroll
        for (int n = 0; n < 4; ++n)
          acc[m][n] = __builtin_amdgcn_mfma_f32_16x16x32_bf16(af[m][kb], bfv[n][kb], acc[m][n], 0, 0, 0);
    asm volatile("s_waitcnt vmcnt(0)" ::: "memory");
    __syncthreads();
  }

  #pragma unroll
  for (int n = 0; n < 4; ++n){
    int col = n0 + qcol * 64 + n * 16 + l15;
    float bvv = BIAS ? bias[col] : 0.0f;
    #pragma unroll
    for (int m = 0; m < 2; ++m){
      int rbase = m0 + qrow * 32 + m * 16 + lk * 4;
      #pragma unroll
      for (int r = 0; r < 4; ++r){
        float x = acc[m][n][r] + bvv;
        if (GELU) x = gelu_f(x);
        int row = rbase + r;
        if (RESID) x += R[(size_t)row * ldr + col];
        if (WF32)  C[(size_t)row * ldc + col] = x;
        if (WBF16) Cb[(size_t)row * ldcb + col] = f2bf(x);
      }
    }
  }
}

// ---------- host ----------
extern "C" void kernel_launch(void* const* d_in, const int* in_sizes, int n_in,
                              void* d_out, int out_size, void* d_ws, size_t ws_size,
                              hipStream_t stream)
{
  (void)in_sizes; (void)n_in; (void)out_size;
  const float* states      = (const float*)d_in[0];
  const float* time_values = (const float*)d_in[1];
  const float* class_sum   = (const float*)d_in[2];
  const float* support     = (const float*)d_in[3];
  const float* trunk_ln_g  = (const float*)d_in[4];
  const float* trunk_ln_b  = (const float*)d_in[5];
  const float* trunk_w1    = (const float*)d_in[6];
  const float* trunk_b1    = (const float*)d_in[7];
  const float* trunk_w2    = (const float*)d_in[8];
  const float* trunk_b2    = (const float*)d_in[9];
  const float* mem_ln_g    = (const float*)d_in[10];
  const float* mem_ln_b    = (const float*)d_in[11];
  const float* mem_w       = (const float*)d_in[12];
  const float* mem_b       = (const float*)d_in[13];
  const float* wq          = (const float*)d_in[14];
  const float* bq          = (const float*)d_in[15];
  const float* wk          = (const float*)d_in[16];
  /* d_in[17] = bk: unused (softmax shift invariance) */
  const float* wv          = (const float*)d_in[18];
  const float* bvp         = (const float*)d_in[19];
  const float* wo          = (const float*)d_in[20];
  const float* bo          = (const float*)d_in[21];
  const float* pre_g       = (const float*)d_in[22];
  const float* pre_b       = (const float*)d_in[23];
  const float* film_w      = (const float*)d_in[24];
  const float* film_b      = (const float*)d_in[25];
  const float* cond_g      = (const float*)d_in[26];
  const float* cond_b      = (const float*)d_in[27];
  const float* cond_w1     = (const float*)d_in[28];
  const float* cond_b1     = (const float*)d_in[29];
  const float* cond_w2     = (const float*)d_in[30];
  const float* cond_b2     = (const float*)d_in[31];
  const float* head_g      = (const float*)d_in[32];
  const float* head_bb     = (const float*)d_in[33];
  const float* head_w1     = (const float*)d_in[34];
  const float* head_b1     = (const float*)d_in[35];
  const float* head_w2     = (const float*)d_in[36];
  const float* head_b2     = (const float*)d_in[37];
  float* out = (float*)d_out;

  char* ws = (char*)d_ws;
  size_t off = 0;
  auto alloc = [&](size_t bytes)->char*{
    char* p = ws + off;
    off += (bytes + 255) & ~(size_t)255;
    return p;
  };
  ushort_t* tw1T   = (ushort_t*)alloc((size_t)640 * 1024 * 2);
  ushort_t* tw2T   = (ushort_t*)alloc((size_t)1024 * 1024 * 2);
  ushort_t* wqT    = (ushort_t*)alloc((size_t)1024 * 1024 * 2);
  ushort_t* wkT    = (ushort_t*)alloc((size_t)1024 * 1024 * 2);
  ushort_t* wvT    = (ushort_t*)alloc((size_t)1024 * 1024 * 2);
  ushort_t* woT    = (ushort_t*)alloc((size_t)1024 * 1024 * 2);
  ushort_t* memw_b = (ushort_t*)alloc((size_t)512 * 1024 * 2);
  ushort_t* filmWT = (ushort_t*)alloc((size_t)512 * 2048 * 2);
  ushort_t* cw1T   = (ushort_t*)alloc((size_t)1024 * 1024 * 2);
  ushort_t* cw2T   = (ushort_t*)alloc((size_t)1024 * 1024 * 2);
  ushort_t* hw1T   = (ushort_t*)alloc((size_t)1024 * 1024 * 2);
  ushort_t* hw2T   = (ushort_t*)alloc((size_t)1024 * 512 * 2);
  ushort_t* K2     = (ushort_t*)alloc((size_t)512 * 1024 * 2);
  ushort_t* V2T    = (ushort_t*)alloc((size_t)1024 * 512 * 2);
  float*    bv2    = (float*)   alloc((size_t)1024 * 4);
  ushort_t* xnb    = (ushort_t*)alloc((size_t)4096 * 640 * 2);
  ushort_t* h1     = (ushort_t*)alloc((size_t)4096 * 1024 * 2);
  float*    gf     = (float*)   alloc((size_t)4096 * 1024 * 4);
  ushort_t* gb     = (ushort_t*)alloc((size_t)4096 * 1024 * 2);
  ushort_t* qb     = (ushort_t*)alloc((size_t)4096 * 1024 * 2);
  ushort_t* U      = (ushort_t*)alloc((size_t)4096 * 4096 * 2);
  ushort_t* Rb     = (ushort_t*)alloc((size_t)4096 * 4096 * 2);
  ushort_t* sumb   = (ushort_t*)alloc((size_t)4096 * 1024 * 2);
  float*    asf    = (float*)   alloc((size_t)4096 * 1024 * 4);
  ushort_t* csb    = (ushort_t*)alloc((size_t)4096 * 512 * 2);
  float*    filmf  = (float*)   alloc((size_t)4096 * 2048 * 4);
  float*    c2f    = (float*)   alloc((size_t)4096 * 1024 * 4);
  ushort_t* cxb    = (ushort_t*)alloc((size_t)4096 * 1024 * 2);
  ushort_t* c1     = (ushort_t*)alloc((size_t)4096 * 1024 * 2);
  float*    cond2f = (float*)   alloc((size_t)4096 * 1024 * 4);
  ushort_t* hxb    = (ushort_t*)alloc((size_t)4096 * 1024 * 2);
  ushort_t* h3     = (ushort_t*)alloc((size_t)4096 * 1024 * 2);
  if (off > ws_size) return;

  // one fused prep launch
  PrepArgs pa;
  int s = 0;
  auto setT = [&](int i, const float* in, ushort_t* o, int K, int N){
    pa.t[i].in = in; pa.t[i].out = o; pa.t[i].K = K; pa.t[i].N = N; pa.t[i].start = s;
    s += (N >> 5) * (K >> 5);
  };
  setT(0, trunk_w1, tw1T, 640, 1024);
  setT(1, trunk_w2, tw2T, 1024, 1024);
  setT(2, wq, wqT, 1024, 1024);
  setT(3, wk, wkT, 1024, 1024);
  setT(4, wv, wvT, 1024, 1024);
  setT(5, wo, woT, 1024, 1024);
  setT(6, film_w, filmWT, 512, 2048);
  setT(7, cond_w1, cw1T, 1024, 1024);
  setT(8, cond_w2, cw2T, 1024, 1024);
  setT(9, head_w1, hw1T, 1024, 1024);
  setT(10, head_w2, hw2T, 1024, 512);
  pa.ntiles_end = s;
  pa.cast1_blocks = (512 * 1024) / 1024;
  pa.cast_end = s + pa.cast1_blocks + (4096 * 512) / 1024;
  pa.memw = mem_w; pa.memwb = memw_b;
  pa.csum = class_sum; pa.csb = csb;
  pa.memb = mem_b; pa.wv = wv; pa.bvp = bvp; pa.bv2 = bv2;
  prep_k<<<pa.cast_end + 4, 256, 0, stream>>>(pa);

  // weight-weight products
  gemm_k<false, false, false, true, false><<<dim3(8, 8, 1), 256, 0, stream>>>(
      memw_b, 1024, 0, wkT, 1024, 0, nullptr, 0, nullptr, 0, 0, K2, 1024, 0, nullptr, 0, 512, 1024, 1024);
  gemm_k<false, false, false, true, false><<<dim3(4, 16, 1), 256, 0, stream>>>(
      wvT, 1024, 0, memw_b, 1024, 0, nullptr, 0, nullptr, 0, 0, V2T, 512, 0, nullptr, 0, 1024, 512, 1024);

  ln_trunk_k<<<4096, 256, 0, stream>>>(states, time_values, trunk_ln_g, trunk_ln_b, xnb);
  gemm_k<true, true, false, true, false><<<dim3(8, 64, 1), 256, 0, stream>>>(
      xnb, 640, 0, tw1T, 640, 0, trunk_b1, 0, nullptr, 0, 0, h1, 1024, 0, nullptr, 0, 4096, 1024, 640);
  gemm_k<false, true, true, true, false><<<dim3(8, 64, 1), 256, 0, stream>>>(
      h1, 1024, 0, tw2T, 1024, 0, trunk_b2, 0, gf, 1024, 0, gb, 1024, 0, nullptr, 0, 4096, 1024, 1024);
  gemm_k<false, true, false, true, false><<<dim3(8, 64, 1), 256, 0, stream>>>(
      gb, 1024, 0, wqT, 1024, 0, bq, 0, nullptr, 0, 0, qb, 1024, 0, nullptr, 0, 4096, 1024, 1024);
  gemm_k<false, false, false, true, false><<<dim3(4, 64, 8), 256, 0, stream>>>(
      qb, 1024, 128, K2, 1024, 128, nullptr, 0, nullptr, 0, 0, U, 4096, 512, nullptr, 0, 4096, 512, 128);

  suppattn_k<<<4096, 256, 0, stream>>>(support, mem_ln_g, mem_ln_b, U, Rb);

  gemm_k<false, true, false, true, false><<<dim3(1, 64, 8), 256, 0, stream>>>(
      Rb, 4096, 512, V2T, 512, 65536, bv2, 128, nullptr, 0, 0, sumb, 1024, 128, nullptr, 0, 4096, 128, 512);

  gemm_k<false, true, true, false, false><<<dim3(8, 64, 1), 256, 0, stream>>>(
      sumb, 1024, 0, woT, 1024, 0, bo, 0, asf, 1024, 0, nullptr, 0, 0, nullptr, 0, 4096, 1024, 1024);
  gemm_k<false, true, true, false, false><<<dim3(16, 64, 1), 256, 0, stream>>>(
      csb, 512, 0, filmWT, 512, 0, film_b, 0, filmf, 2048, 0, nullptr, 0, 0, nullptr, 0, 4096, 2048, 512);

  fuse_film_k<<<4096, 256, 0, stream>>>(gf, asf, filmf, pre_g, pre_b, cond_g, cond_b, c2f, cxb);

  gemm_k<true, true, false, true, false><<<dim3(8, 64, 1), 256, 0, stream>>>(
      cxb, 1024, 0, cw1T, 1024, 0, cond_b1, 0, nullptr, 0, 0, c1, 1024, 0, nullptr, 0, 4096, 1024, 1024);
  gemm_k<false, true, true, false, true><<<dim3(8, 64, 1), 256, 0, stream>>>(
      c1, 1024, 0, cw2T, 1024, 0, cond_b2, 0, cond2f, 1024, 0, nullptr, 0, 0, c2f, 1024, 4096, 1024, 1024);
  ln_rows_k<<<4096, 256, 0, stream>>>(cond2f, head_g, head_bb, hxb, 1024);
  gemm_k<true, true, false, true, false><<<dim3(8, 64, 1), 256, 0, stream>>>(
      hxb, 1024, 0, hw1T, 1024, 0, head_b1, 0, nullptr, 0, 0, h3, 1024, 0, nullptr, 0, 4096, 1024, 1024);
  gemm_k<false, true, true, false, false><<<dim3(4, 64, 1), 256, 0, stream>>>(
      h3, 1024, 0, hw2T, 1024, 0, head_b2, 0, out, 512, 0, nullptr, 0, 0, nullptr, 0, 4096, 512, 1024);
}